// Round 1
// baseline (1511.750 us; speedup 1.0000x reference)
//
#include <hip/hip_runtime.h>

#define BB 2
#define SS 4096
#define DD 768
#define HH 12
#define HDD 64
#define W1C 256
#define NCC 16
#define GG 8

struct GemmArgs {
  const float* W[5];
  const float* bias[5];
};

// ---------------------------------------------------------------------------
// Tiled fp32 GEMM: A[8192x768] x W[768xN] + bias.
// MODE 0: N = 5*768 concatenated (Wq,Wk,Wv,Wkg,Wvg); output scattered to
//         [B,H,S,HD] per-matrix buffers (stride QSZ), matrix 0 scaled 0.125.
// MODE 1: N = 768 (Wo); output row-major [8192x768].
// ---------------------------------------------------------------------------
template<int MODE>
__global__ __launch_bounds__(256) void gemm128(
    const float* __restrict__ A, GemmArgs ga, float* __restrict__ out) {
  __shared__ float As[32][128];
  __shared__ float Bs[32][128];
  const int tid = threadIdx.x;
  const int m0 = blockIdx.y * 128;
  const int ng0 = blockIdx.x * 128;
  const int wsel = (MODE == 0) ? (ng0 / 768) : 0;
  const int n0 = (MODE == 0) ? (ng0 % 768) : ng0;
  const float* __restrict__ W = ga.W[wsel];
  const float* __restrict__ bias = ga.bias[wsel];
  const int tx = tid & 15, ty = tid >> 4;

  float acc[8][8];
#pragma unroll
  for (int i = 0; i < 8; i++)
#pragma unroll
    for (int j = 0; j < 8; j++) acc[i][j] = 0.f;

  for (int k0 = 0; k0 < 768; k0 += 32) {
#pragma unroll
    for (int i = 0; i < 4; i++) {
      int idx4 = tid + i * 256;          // 1024 float4 = 128x32 floats
      int row = idx4 >> 3, c4 = idx4 & 7;
      float4 a = *(const float4*)(A + (size_t)(m0 + row) * 768 + k0 + c4 * 4);
      As[c4 * 4 + 0][row] = a.x;
      As[c4 * 4 + 1][row] = a.y;
      As[c4 * 4 + 2][row] = a.z;
      As[c4 * 4 + 3][row] = a.w;
    }
#pragma unroll
    for (int i = 0; i < 4; i++) {
      int idx4 = tid + i * 256;          // 32x128 floats
      int row = idx4 >> 5, c4 = idx4 & 31;
      *(float4*)&Bs[row][c4 * 4] =
          *(const float4*)(W + (size_t)(k0 + row) * 768 + n0 + c4 * 4);
    }
    __syncthreads();
#pragma unroll
    for (int kk = 0; kk < 32; kk++) {
      float a[8], bb[8];
      *(float4*)&a[0] = *(float4*)&As[kk][ty * 8];
      *(float4*)&a[4] = *(float4*)&As[kk][ty * 8 + 4];
      *(float4*)&bb[0] = *(float4*)&Bs[kk][tx * 8];
      *(float4*)&bb[4] = *(float4*)&Bs[kk][tx * 8 + 4];
#pragma unroll
      for (int i = 0; i < 8; i++)
#pragma unroll
        for (int j = 0; j < 8; j++) acc[i][j] = fmaf(a[i], bb[j], acc[i][j]);
    }
    __syncthreads();
  }

  if (MODE == 0) {
    const float scale = (wsel == 0) ? 0.125f : 1.0f;
    float* outw = out + (size_t)wsel * ((size_t)BB * HH * SS * HDD);
#pragma unroll
    for (int i = 0; i < 8; i++) {
      int m = m0 + ty * 8 + i;
      int b = m >> 12, s = m & 4095;
#pragma unroll
      for (int jj = 0; jj < 8; jj += 4) {
        int c = n0 + tx * 8 + jj;
        int h = c >> 6, hd = c & 63;
        float4 o;
        o.x = (acc[i][jj + 0] + bias[c + 0]) * scale;
        o.y = (acc[i][jj + 1] + bias[c + 1]) * scale;
        o.z = (acc[i][jj + 2] + bias[c + 2]) * scale;
        o.w = (acc[i][jj + 3] + bias[c + 3]) * scale;
        *(float4*)(outw + (((size_t)(b * HH + h) * SS + s) * HDD + hd)) = o;
      }
    }
  } else {
#pragma unroll
    for (int i = 0; i < 8; i++) {
      int m = m0 + ty * 8 + i;
#pragma unroll
      for (int jj = 0; jj < 8; jj += 4) {
        int c = n0 + tx * 8 + jj;
        float4 o;
        o.x = acc[i][jj + 0] + bias[c + 0];
        o.y = acc[i][jj + 1] + bias[c + 1];
        o.z = acc[i][jj + 2] + bias[c + 2];
        o.w = acc[i][jj + 3] + bias[c + 3];
        *(float4*)(out + (size_t)m * 768 + c) = o;
      }
    }
  }
}

// ---------------------------------------------------------------------------
// Banded sliding-window attention + global-key columns.
// One WG of 256 threads per (chunk, head, batch); thread t = query row t.
// Single-pass softmax without max subtraction (scores are O(1); masked -> 0).
// Writes ATT in merged [B,S,D] layout.
// ---------------------------------------------------------------------------
__global__ __launch_bounds__(256) void band_attn(
    const float* __restrict__ Q, const float* __restrict__ K,
    const float* __restrict__ V, const int* __restrict__ amask,
    float* __restrict__ ATT) {
  const int c = blockIdx.x;   // chunk 0..15
  const int h = blockIdx.y;   // head
  const int b = blockIdx.z;   // batch
  const int t = threadIdx.x;  // query row within chunk
  const int q_abs = c * W1C + t;
  const size_t bh = (size_t)(b * HH + h) * SS;

  __shared__ float Kl[128 * 64];
  __shared__ float Vl[128 * 64];
  __shared__ int Ml[128];

  float q[64];
  {
    const float4* qr = (const float4*)(Q + (bh + q_abs) * 64);
#pragma unroll
    for (int d4 = 0; d4 < 16; d4++) {
      float4 f = qr[d4];
      q[d4 * 4 + 0] = f.x; q[d4 * 4 + 1] = f.y;
      q[d4 * 4 + 2] = f.z; q[d4 * 4 + 3] = f.w;
    }
  }
  float acc[64];
#pragma unroll
  for (int d = 0; d < 64; d++) acc[d] = 0.f;
  float denom = 0.f;

  // ---- global-key columns (keys 0..G-1, regular k/v projections) ----
  for (int j = 0; j < GG; j++) {
    const float4* kr = (const float4*)(K + (bh + j) * 64);
    float s = 0.f;
#pragma unroll
    for (int d4 = 0; d4 < 16; d4++) {
      float4 kv = kr[d4];
      s += q[d4 * 4 + 0] * kv.x + q[d4 * 4 + 1] * kv.y +
           q[d4 * 4 + 2] * kv.z + q[d4 * 4 + 3] * kv.w;
    }
    float p = (amask[b * SS + j] >= 0) ? __expf(s) : 0.f;
    denom += p;
    const float4* vr = (const float4*)(V + (bh + j) * 64);
#pragma unroll
    for (int d4 = 0; d4 < 16; d4++) {
      float4 vv = vr[d4];
      acc[d4 * 4 + 0] = fmaf(p, vv.x, acc[d4 * 4 + 0]);
      acc[d4 * 4 + 1] = fmaf(p, vv.y, acc[d4 * 4 + 1]);
      acc[d4 * 4 + 2] = fmaf(p, vv.z, acc[d4 * 4 + 2]);
      acc[d4 * 4 + 3] = fmaf(p, vv.w, acc[d4 * 4 + 3]);
    }
  }

  // ---- banded window: 3*W1 = 768 keys in 6 chunks of 128 ----
  for (int kt = 0; kt < 6; kt++) {
    const int j0 = c * W1C - W1C + kt * 128;
    // cooperative stage of K/V rows j0..j0+127 (zero-filled out of range)
#pragma unroll
    for (int i = 0; i < 8; i++) {
      int idx4 = t + i * 256;  // 2048 float4 = 128 rows x 16 float4
      int row = idx4 >> 4, c4 = idx4 & 15;
      int j = j0 + row;
      float4 kv = make_float4(0.f, 0.f, 0.f, 0.f);
      float4 vv = make_float4(0.f, 0.f, 0.f, 0.f);
      if ((unsigned)j < (unsigned)SS) {
        kv = *(const float4*)(K + (bh + j) * 64 + c4 * 4);
        vv = *(const float4*)(V + (bh + j) * 64 + c4 * 4);
      }
      *(float4*)&Kl[idx4 * 4] = kv;
      *(float4*)&Vl[idx4 * 4] = vv;
    }
    if (t < 128) {
      int j = j0 + t;
      Ml[t] = ((unsigned)j < (unsigned)SS) ? amask[b * SS + j] : -1;
    }
    __syncthreads();

    for (int kk = 0; kk < 128; kk++) {
      const int j = j0 + kk;
      float s = 0.f;
      const float4* kr = (const float4*)&Kl[kk * 64];
#pragma unroll
      for (int d4 = 0; d4 < 16; d4++) {
        float4 kv = kr[d4];
        s += q[d4 * 4 + 0] * kv.x + q[d4 * 4 + 1] * kv.y +
             q[d4 * 4 + 2] * kv.z + q[d4 * 4 + 3] * kv.w;
      }
      const int dd = j - q_abs;
      const bool ok = (dd >= -W1C) && (dd <= W1C) &&
                      ((unsigned)j < (unsigned)SS) && (Ml[kk] >= 0);
      float p = ok ? __expf(s) : 0.f;
      denom += p;
      const float4* vr = (const float4*)&Vl[kk * 64];
#pragma unroll
      for (int d4 = 0; d4 < 16; d4++) {
        float4 vv = vr[d4];
        acc[d4 * 4 + 0] = fmaf(p, vv.x, acc[d4 * 4 + 0]);
        acc[d4 * 4 + 1] = fmaf(p, vv.y, acc[d4 * 4 + 1]);
        acc[d4 * 4 + 2] = fmaf(p, vv.z, acc[d4 * 4 + 2]);
        acc[d4 * 4 + 3] = fmaf(p, vv.w, acc[d4 * 4 + 3]);
      }
    }
    __syncthreads();
  }

  const float rowscale =
      (amask[b * SS + q_abs] >= 0) ? (1.0f / denom) : 0.f;
  float* orow = ATT + ((size_t)b * SS + q_abs) * DD + h * 64;
#pragma unroll
  for (int d4 = 0; d4 < 16; d4++) {
    float4 o;
    o.x = acc[d4 * 4 + 0] * rowscale;
    o.y = acc[d4 * 4 + 1] * rowscale;
    o.z = acc[d4 * 4 + 2] * rowscale;
    o.w = acc[d4 * 4 + 3] * rowscale;
    *(float4*)(orow + d4 * 4) = o;
  }
}

// ---------------------------------------------------------------------------
// Global-token attention: one wave per (b,h,qi). Computes qg row inline,
// full softmax over S keys of KG/VG, writes OG[b,h,qi,:].
// ---------------------------------------------------------------------------
__global__ __launch_bounds__(64) void global_attn(
    const float* __restrict__ hs, const int* __restrict__ amask,
    const float* __restrict__ Wqg, const float* __restrict__ bqg,
    const float* __restrict__ KG, const float* __restrict__ VG,
    float* __restrict__ OG) {
  const int l = threadIdx.x;
  const int id = blockIdx.x;  // B*H*G = 192
  const int qi = id & 7;
  const int h = (id >> 3) % HH;
  const int b = id / (HH * GG);

  __shared__ float qrow[64];
  __shared__ float red[64 * 65];

  // q element for this lane: (hs[b,qi,:] . Wqg[:, h*64+l] + bqg) * scale
  float aq = bqg[h * 64 + l];
  const float* hsrow = hs + ((size_t)b * SS + qi) * DD;
  for (int t = 0; t < DD; t++)
    aq = fmaf(hsrow[t], Wqg[(size_t)t * DD + h * 64 + l], aq);
  qrow[l] = aq * 0.125f;
  __syncthreads();

  float q[64];
#pragma unroll
  for (int d = 0; d < 64; d++) q[d] = qrow[d];

  float accv[64];
#pragma unroll
  for (int d = 0; d < 64; d++) accv[d] = 0.f;
  float denom = 0.f;

  const float* kbase = KG + ((size_t)(b * HH + h)) * SS * 64;
  const float* vbase = VG + ((size_t)(b * HH + h)) * SS * 64;
  for (int t = 0; t < 64; t++) {
    const int j = l + t * 64;
    const float4* kr = (const float4*)(kbase + (size_t)j * 64);
    float s = 0.f;
#pragma unroll
    for (int d4 = 0; d4 < 16; d4++) {
      float4 kv = kr[d4];
      s += q[d4 * 4 + 0] * kv.x + q[d4 * 4 + 1] * kv.y +
           q[d4 * 4 + 2] * kv.z + q[d4 * 4 + 3] * kv.w;
    }
    float p = (amask[b * SS + j] >= 0) ? __expf(s) : 0.f;
    denom += p;
    const float4* vr = (const float4*)(vbase + (size_t)j * 64);
#pragma unroll
    for (int d4 = 0; d4 < 16; d4++) {
      float4 vv = vr[d4];
      accv[d4 * 4 + 0] = fmaf(p, vv.x, accv[d4 * 4 + 0]);
      accv[d4 * 4 + 1] = fmaf(p, vv.y, accv[d4 * 4 + 1]);
      accv[d4 * 4 + 2] = fmaf(p, vv.z, accv[d4 * 4 + 2]);
      accv[d4 * 4 + 3] = fmaf(p, vv.w, accv[d4 * 4 + 3]);
    }
  }

#pragma unroll
  for (int d = 0; d < 64; d++) red[l * 65 + d] = accv[d];
  red[l * 65 + 64] = denom;
  __syncthreads();

  float od = 0.f, dsum = 0.f;
  for (int t = 0; t < 64; t++) {
    od += red[t * 65 + l];
    dsum += red[t * 65 + 64];
  }
  OG[(((size_t)(b * HH + h)) * GG + qi) * 64 + l] = od / dsum;
}

// ---------------------------------------------------------------------------
// Copy OG into ATT rows s < G (merged [B,S,D] layout).
// ---------------------------------------------------------------------------
__global__ __launch_bounds__(256) void merge_og(const float* __restrict__ OG,
                                                float* __restrict__ ATT) {
  int i = blockIdx.x * 256 + threadIdx.x;  // B*G*D = 12288
  if (i >= BB * GG * DD) return;
  int d = i % DD;
  int qi = (i / DD) % GG;
  int b = i / (DD * GG);
  int h = d >> 6, hd = d & 63;
  ATT[((size_t)b * SS + qi) * DD + d] =
      OG[(((size_t)(b * HH + h)) * GG + qi) * 64 + hd];
}

// ---------------------------------------------------------------------------
extern "C" void kernel_launch(void* const* d_in, const int* in_sizes, int n_in,
                              void* d_out, int out_size, void* d_ws,
                              size_t ws_size, hipStream_t stream) {
  const float* hs = (const float*)d_in[0];
  const int* amask = (const int*)d_in[1];
  const float* Wq = (const float*)d_in[2];
  const float* bq = (const float*)d_in[3];
  const float* Wk = (const float*)d_in[4];
  const float* bk = (const float*)d_in[5];
  const float* Wv = (const float*)d_in[6];
  const float* bv = (const float*)d_in[7];
  const float* Wqg = (const float*)d_in[8];
  const float* bqg = (const float*)d_in[9];
  const float* Wkg = (const float*)d_in[10];
  const float* bkg = (const float*)d_in[11];
  const float* Wvg = (const float*)d_in[12];
  const float* bvg = (const float*)d_in[13];
  const float* Wo = (const float*)d_in[14];
  const float* bo = (const float*)d_in[15];
  float* out = (float*)d_out;

  float* wsf = (float*)d_ws;
  const size_t QSZ = (size_t)BB * HH * SS * HDD;  // 6291456 floats
  float* Qb = wsf;
  float* Kb = wsf + QSZ;
  float* Vb = wsf + 2 * QSZ;
  float* KGb = wsf + 3 * QSZ;
  float* VGb = wsf + 4 * QSZ;
  float* OGb = wsf + 5 * QSZ;  // B*H*G*64 = 12288 floats
  float* ATT = KGb;            // reuse KG buffer after global_attn consumed it

  // 1) fused projections: Q,K,V,KG,VG
  GemmArgs ga0;
  ga0.W[0] = Wq; ga0.W[1] = Wk; ga0.W[2] = Wv; ga0.W[3] = Wkg; ga0.W[4] = Wvg;
  ga0.bias[0] = bq; ga0.bias[1] = bk; ga0.bias[2] = bv;
  ga0.bias[3] = bkg; ga0.bias[4] = bvg;
  hipLaunchKernelGGL((gemm128<0>), dim3(30, 64), dim3(256), 0, stream, hs, ga0,
                     wsf);

  // 2) global-token attention (reads KG,VG) -> OG
  hipLaunchKernelGGL(global_attn, dim3(192), dim3(64), 0, stream, hs, amask,
                     Wqg, bqg, KGb, VGb, OGb);

  // 3) banded attention -> ATT (overwrites KG buffer; safe: stream-ordered)
  hipLaunchKernelGGL(band_attn, dim3(NCC, HH, BB), dim3(256), 0, stream, Qb,
                     Kb, Vb, amask, ATT);

  // 4) merge global-token rows into ATT
  hipLaunchKernelGGL(merge_og, dim3(48), dim3(256), 0, stream, OGb, ATT);

  // 5) output projection
  GemmArgs ga1;
  for (int i = 0; i < 5; i++) { ga1.W[i] = Wo; ga1.bias[i] = bo; }
  hipLaunchKernelGGL((gemm128<1>), dim3(6, 64), dim3(256), 0, stream, ATT, ga1,
                     out);
}

// Round 2
// 1290.558 us; speedup vs baseline: 1.1714x; 1.1714x over previous
//
#include <hip/hip_runtime.h>

#define BB 2
#define SS 4096
#define DD 768
#define HH 12
#define HDD 64
#define W1C 256
#define NCC 16
#define GG 8

struct GemmArgs {
  const float* W[5];
  const float* bias[5];
};

// ---------------------------------------------------------------------------
// Tiled fp32 GEMM: A[8192x768] x W[768xN] + bias.
// MODE 0: N = 5*768 concatenated (Wq,Wk,Wv,Wkg,Wvg); output scattered to
//         [B,H,S,HD] per-matrix buffers (stride QSZ), matrix 0 scaled 0.125.
// MODE 1: N = 768 (Wo); output row-major [8192x768].
// ---------------------------------------------------------------------------
template<int MODE>
__global__ __launch_bounds__(256) void gemm128(
    const float* __restrict__ A, GemmArgs ga, float* __restrict__ out) {
  __shared__ float As[32][128];
  __shared__ float Bs[32][128];
  const int tid = threadIdx.x;
  const int m0 = blockIdx.y * 128;
  const int ng0 = blockIdx.x * 128;
  const int wsel = (MODE == 0) ? (ng0 / 768) : 0;
  const int n0 = (MODE == 0) ? (ng0 % 768) : ng0;
  const float* __restrict__ W = ga.W[wsel];
  const float* __restrict__ bias = ga.bias[wsel];
  const int tx = tid & 15, ty = tid >> 4;

  float acc[8][8];
#pragma unroll
  for (int i = 0; i < 8; i++)
#pragma unroll
    for (int j = 0; j < 8; j++) acc[i][j] = 0.f;

  for (int k0 = 0; k0 < 768; k0 += 32) {
#pragma unroll
    for (int i = 0; i < 4; i++) {
      int idx4 = tid + i * 256;          // 1024 float4 = 128x32 floats
      int row = idx4 >> 3, c4 = idx4 & 7;
      float4 a = *(const float4*)(A + (size_t)(m0 + row) * 768 + k0 + c4 * 4);
      As[c4 * 4 + 0][row] = a.x;
      As[c4 * 4 + 1][row] = a.y;
      As[c4 * 4 + 2][row] = a.z;
      As[c4 * 4 + 3][row] = a.w;
    }
#pragma unroll
    for (int i = 0; i < 4; i++) {
      int idx4 = tid + i * 256;          // 32x128 floats
      int row = idx4 >> 5, c4 = idx4 & 31;
      *(float4*)&Bs[row][c4 * 4] =
          *(const float4*)(W + (size_t)(k0 + row) * 768 + n0 + c4 * 4);
    }
    __syncthreads();
#pragma unroll
    for (int kk = 0; kk < 32; kk++) {
      float a[8], bb[8];
      *(float4*)&a[0] = *(float4*)&As[kk][ty * 8];
      *(float4*)&a[4] = *(float4*)&As[kk][ty * 8 + 4];
      *(float4*)&bb[0] = *(float4*)&Bs[kk][tx * 8];
      *(float4*)&bb[4] = *(float4*)&Bs[kk][tx * 8 + 4];
#pragma unroll
      for (int i = 0; i < 8; i++)
#pragma unroll
        for (int j = 0; j < 8; j++) acc[i][j] = fmaf(a[i], bb[j], acc[i][j]);
    }
    __syncthreads();
  }

  if (MODE == 0) {
    const float scale = (wsel == 0) ? 0.125f : 1.0f;
    float* outw = out + (size_t)wsel * ((size_t)BB * HH * SS * HDD);
#pragma unroll
    for (int i = 0; i < 8; i++) {
      int m = m0 + ty * 8 + i;
      int b = m >> 12, s = m & 4095;
#pragma unroll
      for (int jj = 0; jj < 8; jj += 4) {
        int c = n0 + tx * 8 + jj;
        int h = c >> 6, hd = c & 63;
        float4 o;
        o.x = (acc[i][jj + 0] + bias[c + 0]) * scale;
        o.y = (acc[i][jj + 1] + bias[c + 1]) * scale;
        o.z = (acc[i][jj + 2] + bias[c + 2]) * scale;
        o.w = (acc[i][jj + 3] + bias[c + 3]) * scale;
        *(float4*)(outw + (((size_t)(b * HH + h) * SS + s) * HDD + hd)) = o;
      }
    }
  } else {
#pragma unroll
    for (int i = 0; i < 8; i++) {
      int m = m0 + ty * 8 + i;
#pragma unroll
      for (int jj = 0; jj < 8; jj += 4) {
        int c = n0 + tx * 8 + jj;
        float4 o;
        o.x = acc[i][jj + 0] + bias[c + 0];
        o.y = acc[i][jj + 1] + bias[c + 1];
        o.z = acc[i][jj + 2] + bias[c + 2];
        o.w = acc[i][jj + 3] + bias[c + 3];
        *(float4*)(out + (size_t)m * 768 + c) = o;
      }
    }
  }
}

// ---------------------------------------------------------------------------
// Banded sliding-window attention + global-key columns. Restructured for
// occupancy: one WG of 256 threads handles 64 queries; 4 threads per query,
// each owning a 16-dim slice. Score dot reduced over the 4-lane group via
// shfl_xor. K/V staged in 64-key LDS tiles (33 KB -> 4 WG/CU).
// Grid: (NCC*4, HH, BB) = 1536 WGs.
// ---------------------------------------------------------------------------
__global__ __launch_bounds__(256) void band_attn(
    const float* __restrict__ Q, const float* __restrict__ K,
    const float* __restrict__ V, const int* __restrict__ amask,
    float* __restrict__ ATT) {
  const int sub = blockIdx.x & 3;
  const int c = blockIdx.x >> 2;
  const int h = blockIdx.y;
  const int b = blockIdx.z;
  const int t = threadIdx.x;
  const int qi = t >> 2;       // query 0..63 within sub-chunk
  const int sl = t & 3;        // dim slice 0..3 (16 dims each)
  const int q0 = c * W1C + sub * 64;
  const int q_abs = q0 + qi;
  const size_t bh = (size_t)(b * HH + h) * SS;

  __shared__ float Kl[64 * 64];
  __shared__ float Vl[64 * 64];
  __shared__ int Ml[64];

  // q slice: 16 dims
  float q[16];
  {
    const float4* qr = (const float4*)(Q + (bh + q_abs) * 64 + sl * 16);
#pragma unroll
    for (int d4 = 0; d4 < 4; d4++) {
      float4 f = qr[d4];
      q[d4 * 4 + 0] = f.x; q[d4 * 4 + 1] = f.y;
      q[d4 * 4 + 2] = f.z; q[d4 * 4 + 3] = f.w;
    }
  }
  float acc[16];
#pragma unroll
  for (int d = 0; d < 16; d++) acc[d] = 0.f;
  float denom = 0.f;

  // ---- global-key columns (keys 0..G-1, regular k/v projections) ----
#pragma unroll
  for (int j = 0; j < GG; j++) {
    const float4* kr = (const float4*)(K + (bh + j) * 64 + sl * 16);
    float s0 = 0.f, s1 = 0.f, s2 = 0.f, s3 = 0.f;
#pragma unroll
    for (int d4 = 0; d4 < 4; d4++) {
      float4 kv = kr[d4];
      s0 = fmaf(q[d4 * 4 + 0], kv.x, s0);
      s1 = fmaf(q[d4 * 4 + 1], kv.y, s1);
      s2 = fmaf(q[d4 * 4 + 2], kv.z, s2);
      s3 = fmaf(q[d4 * 4 + 3], kv.w, s3);
    }
    float s = (s0 + s1) + (s2 + s3);
    s += __shfl_xor(s, 1);
    s += __shfl_xor(s, 2);
    float p = (amask[b * SS + j] >= 0) ? __expf(s) : 0.f;
    denom += p;
    const float4* vr = (const float4*)(V + (bh + j) * 64 + sl * 16);
#pragma unroll
    for (int d4 = 0; d4 < 4; d4++) {
      float4 vv = vr[d4];
      acc[d4 * 4 + 0] = fmaf(p, vv.x, acc[d4 * 4 + 0]);
      acc[d4 * 4 + 1] = fmaf(p, vv.y, acc[d4 * 4 + 1]);
      acc[d4 * 4 + 2] = fmaf(p, vv.z, acc[d4 * 4 + 2]);
      acc[d4 * 4 + 3] = fmaf(p, vv.w, acc[d4 * 4 + 3]);
    }
  }

  // ---- banded window: 64 queries span [q0-256, q0+320) = 9 tiles of 64 ----
  for (int kt = 0; kt < 9; kt++) {
    const int j0 = q0 - W1C + kt * 64;
    // cooperative stage of K/V rows j0..j0+63 (zero-filled out of range)
#pragma unroll
    for (int i = 0; i < 4; i++) {
      int idx4 = t + i * 256;  // 1024 float4 = 64 rows x 16 float4
      int row = idx4 >> 4, c4 = idx4 & 15;
      int j = j0 + row;
      float4 kv = make_float4(0.f, 0.f, 0.f, 0.f);
      float4 vv = make_float4(0.f, 0.f, 0.f, 0.f);
      if ((unsigned)j < (unsigned)SS) {
        kv = *(const float4*)(K + (bh + j) * 64 + c4 * 4);
        vv = *(const float4*)(V + (bh + j) * 64 + c4 * 4);
      }
      *(float4*)&Kl[idx4 * 4] = kv;
      *(float4*)&Vl[idx4 * 4] = vv;
    }
    if (t < 64) {
      int j = j0 + t;
      Ml[t] = ((unsigned)j < (unsigned)SS) ? amask[b * SS + j] : -1;
    }
    __syncthreads();

    for (int kk = 0; kk < 64; kk++) {
      const int j = j0 + kk;
      const float4* kr = (const float4*)&Kl[kk * 64 + sl * 16];
      float s0 = 0.f, s1 = 0.f, s2 = 0.f, s3 = 0.f;
#pragma unroll
      for (int d4 = 0; d4 < 4; d4++) {
        float4 kv = kr[d4];
        s0 = fmaf(q[d4 * 4 + 0], kv.x, s0);
        s1 = fmaf(q[d4 * 4 + 1], kv.y, s1);
        s2 = fmaf(q[d4 * 4 + 2], kv.z, s2);
        s3 = fmaf(q[d4 * 4 + 3], kv.w, s3);
      }
      float s = (s0 + s1) + (s2 + s3);
      s += __shfl_xor(s, 1);
      s += __shfl_xor(s, 2);
      const int dd = j - q_abs;
      const bool ok = (dd >= -W1C) && (dd <= W1C) &&
                      ((unsigned)j < (unsigned)SS) && (Ml[kk] >= 0);
      float p = ok ? __expf(s) : 0.f;
      denom += p;
      const float4* vr = (const float4*)&Vl[kk * 64 + sl * 16];
#pragma unroll
      for (int d4 = 0; d4 < 4; d4++) {
        float4 vv = vr[d4];
        acc[d4 * 4 + 0] = fmaf(p, vv.x, acc[d4 * 4 + 0]);
        acc[d4 * 4 + 1] = fmaf(p, vv.y, acc[d4 * 4 + 1]);
        acc[d4 * 4 + 2] = fmaf(p, vv.z, acc[d4 * 4 + 2]);
        acc[d4 * 4 + 3] = fmaf(p, vv.w, acc[d4 * 4 + 3]);
      }
    }
    __syncthreads();
  }

  const float rowscale =
      (amask[b * SS + q_abs] >= 0) ? (1.0f / denom) : 0.f;
  float* orow = ATT + ((size_t)b * SS + q_abs) * DD + h * 64 + sl * 16;
#pragma unroll
  for (int d4 = 0; d4 < 4; d4++) {
    float4 o;
    o.x = acc[d4 * 4 + 0] * rowscale;
    o.y = acc[d4 * 4 + 1] * rowscale;
    o.z = acc[d4 * 4 + 2] * rowscale;
    o.w = acc[d4 * 4 + 3] * rowscale;
    *(float4*)(orow + d4 * 4) = o;
  }
}

// ---------------------------------------------------------------------------
// Global-token attention: one wave per (b,h,qi). Computes qg row inline,
// full softmax over S keys of KG/VG, writes OG[b,h,qi,:].
// ---------------------------------------------------------------------------
__global__ __launch_bounds__(64) void global_attn(
    const float* __restrict__ hs, const int* __restrict__ amask,
    const float* __restrict__ Wqg, const float* __restrict__ bqg,
    const float* __restrict__ KG, const float* __restrict__ VG,
    float* __restrict__ OG) {
  const int l = threadIdx.x;
  const int id = blockIdx.x;  // B*H*G = 192
  const int qi = id & 7;
  const int h = (id >> 3) % HH;
  const int b = id / (HH * GG);

  __shared__ float qrow[64];
  __shared__ float red[64 * 65];

  // q element for this lane: (hs[b,qi,:] . Wqg[:, h*64+l] + bqg) * scale
  float aq = bqg[h * 64 + l];
  const float* hsrow = hs + ((size_t)b * SS + qi) * DD;
  for (int t = 0; t < DD; t++)
    aq = fmaf(hsrow[t], Wqg[(size_t)t * DD + h * 64 + l], aq);
  qrow[l] = aq * 0.125f;
  __syncthreads();

  float q[64];
#pragma unroll
  for (int d = 0; d < 64; d++) q[d] = qrow[d];

  float accv[64];
#pragma unroll
  for (int d = 0; d < 64; d++) accv[d] = 0.f;
  float denom = 0.f;

  const float* kbase = KG + ((size_t)(b * HH + h)) * SS * 64;
  const float* vbase = VG + ((size_t)(b * HH + h)) * SS * 64;
  for (int t = 0; t < 64; t++) {
    const int j = l + t * 64;
    const float4* kr = (const float4*)(kbase + (size_t)j * 64);
    float s = 0.f;
#pragma unroll
    for (int d4 = 0; d4 < 16; d4++) {
      float4 kv = kr[d4];
      s += q[d4 * 4 + 0] * kv.x + q[d4 * 4 + 1] * kv.y +
           q[d4 * 4 + 2] * kv.z + q[d4 * 4 + 3] * kv.w;
    }
    float p = (amask[b * SS + j] >= 0) ? __expf(s) : 0.f;
    denom += p;
    const float4* vr = (const float4*)(vbase + (size_t)j * 64);
#pragma unroll
    for (int d4 = 0; d4 < 16; d4++) {
      float4 vv = vr[d4];
      accv[d4 * 4 + 0] = fmaf(p, vv.x, accv[d4 * 4 + 0]);
      accv[d4 * 4 + 1] = fmaf(p, vv.y, accv[d4 * 4 + 1]);
      accv[d4 * 4 + 2] = fmaf(p, vv.z, accv[d4 * 4 + 2]);
      accv[d4 * 4 + 3] = fmaf(p, vv.w, accv[d4 * 4 + 3]);
    }
  }

#pragma unroll
  for (int d = 0; d < 64; d++) red[l * 65 + d] = accv[d];
  red[l * 65 + 64] = denom;
  __syncthreads();

  float od = 0.f, dsum = 0.f;
  for (int t = 0; t < 64; t++) {
    od += red[t * 65 + l];
    dsum += red[t * 65 + 64];
  }
  OG[(((size_t)(b * HH + h)) * GG + qi) * 64 + l] = od / dsum;
}

// ---------------------------------------------------------------------------
// Copy OG into ATT rows s < G (merged [B,S,D] layout).
// ---------------------------------------------------------------------------
__global__ __launch_bounds__(256) void merge_og(const float* __restrict__ OG,
                                                float* __restrict__ ATT) {
  int i = blockIdx.x * 256 + threadIdx.x;  // B*G*D = 12288
  if (i >= BB * GG * DD) return;
  int d = i % DD;
  int qi = (i / DD) % GG;
  int b = i / (DD * GG);
  int h = d >> 6, hd = d & 63;
  ATT[((size_t)b * SS + qi) * DD + d] =
      OG[(((size_t)(b * HH + h)) * GG + qi) * 64 + hd];
}

// ---------------------------------------------------------------------------
extern "C" void kernel_launch(void* const* d_in, const int* in_sizes, int n_in,
                              void* d_out, int out_size, void* d_ws,
                              size_t ws_size, hipStream_t stream) {
  const float* hs = (const float*)d_in[0];
  const int* amask = (const int*)d_in[1];
  const float* Wq = (const float*)d_in[2];
  const float* bq = (const float*)d_in[3];
  const float* Wk = (const float*)d_in[4];
  const float* bk = (const float*)d_in[5];
  const float* Wv = (const float*)d_in[6];
  const float* bv = (const float*)d_in[7];
  const float* Wqg = (const float*)d_in[8];
  const float* bqg = (const float*)d_in[9];
  const float* Wkg = (const float*)d_in[10];
  const float* bkg = (const float*)d_in[11];
  const float* Wvg = (const float*)d_in[12];
  const float* bvg = (const float*)d_in[13];
  const float* Wo = (const float*)d_in[14];
  const float* bo = (const float*)d_in[15];
  float* out = (float*)d_out;

  float* wsf = (float*)d_ws;
  const size_t QSZ = (size_t)BB * HH * SS * HDD;  // 6291456 floats
  float* Qb = wsf;
  float* Kb = wsf + QSZ;
  float* Vb = wsf + 2 * QSZ;
  float* KGb = wsf + 3 * QSZ;
  float* VGb = wsf + 4 * QSZ;
  float* OGb = wsf + 5 * QSZ;  // B*H*G*64 = 12288 floats
  float* ATT = KGb;            // reuse KG buffer after global_attn consumed it

  // 1) fused projections: Q,K,V,KG,VG
  GemmArgs ga0;
  ga0.W[0] = Wq; ga0.W[1] = Wk; ga0.W[2] = Wv; ga0.W[3] = Wkg; ga0.W[4] = Wvg;
  ga0.bias[0] = bq; ga0.bias[1] = bk; ga0.bias[2] = bv;
  ga0.bias[3] = bkg; ga0.bias[4] = bvg;
  hipLaunchKernelGGL((gemm128<0>), dim3(30, 64), dim3(256), 0, stream, hs, ga0,
                     wsf);

  // 2) global-token attention (reads KG,VG) -> OG
  hipLaunchKernelGGL(global_attn, dim3(192), dim3(64), 0, stream, hs, amask,
                     Wqg, bqg, KGb, VGb, OGb);

  // 3) banded attention -> ATT (overwrites KG buffer; safe: stream-ordered)
  hipLaunchKernelGGL(band_attn, dim3(NCC * 4, HH, BB), dim3(256), 0, stream,
                     Qb, Kb, Vb, amask, ATT);

  // 4) merge global-token rows into ATT
  hipLaunchKernelGGL(merge_og, dim3(48), dim3(256), 0, stream, OGb, ATT);

  // 5) output projection
  GemmArgs ga1;
  for (int i = 0; i < 5; i++) { ga1.W[i] = Wo; ga1.bias[i] = bo; }
  hipLaunchKernelGGL((gemm128<1>), dim3(6, 64), dim3(256), 0, stream, ATT, ga1,
                     out);
}

// Round 3
// 646.963 us; speedup vs baseline: 2.3367x; 1.9948x over previous
//
#include <hip/hip_runtime.h>

#define BB 2
#define SS 4096
#define DD 768
#define HH 12
#define HDD 64
#define W1C 256
#define NCC 16
#define GG 8

typedef unsigned short u16;
typedef __attribute__((ext_vector_type(8))) unsigned short u16x8;
typedef __attribute__((ext_vector_type(8))) short s16x8;
typedef __attribute__((ext_vector_type(4))) float f32x4;

__device__ __forceinline__ float b2f(u16 u) {
  union { unsigned int i; float f; } v;
  v.i = ((unsigned int)u) << 16;
  return v.f;
}
__device__ __forceinline__ u16 f2b(float f) {
  union { float f; unsigned int i; } v;
  v.f = f;
  unsigned int r = v.i + 0x7FFFu + ((v.i >> 16) & 1u);
  return (u16)(r >> 16);
}

__device__ __forceinline__ void load_lds16(const void* g, void* l) {
  __builtin_amdgcn_global_load_lds(
      (const __attribute__((address_space(1))) unsigned int*)g,
      (__attribute__((address_space(3))) unsigned int*)l, 16, 0, 0);
}

// ---------------------------------------------------------------------------
// fp32 -> bf16 bulk convert (8 elems/thread)
// ---------------------------------------------------------------------------
__global__ __launch_bounds__(256) void cvt_f32_bf16(
    const float* __restrict__ in, u16* __restrict__ out, int n8) {
  int i = blockIdx.x * 256 + threadIdx.x;
  if (i >= n8) return;
  const float4* p = (const float4*)(in + (size_t)i * 8);
  float4 a = p[0], b = p[1];
  u16x8 o;
  o[0] = f2b(a.x); o[1] = f2b(a.y); o[2] = f2b(a.z); o[3] = f2b(a.w);
  o[4] = f2b(b.x); o[5] = f2b(b.y); o[6] = f2b(b.z); o[7] = f2b(b.w);
  *(u16x8*)(out + (size_t)i * 8) = o;
}

// ---------------------------------------------------------------------------
// Transpose + convert 6 weight matrices [768][768] fp32 (W[k][n]) into
// WT[mat][n][k] bf16. 64x64 LDS tiles.
// ---------------------------------------------------------------------------
struct WtArgs { const float* W[6]; };

__global__ __launch_bounds__(256) void transpose_wt(WtArgs wa,
                                                    u16* __restrict__ WT) {
  __shared__ float T[64][65];
  const int mat = blockIdx.z;
  const int k0 = blockIdx.y * 64;
  const int n0 = blockIdx.x * 64;
  const float* __restrict__ W = wa.W[mat];
  const int t = threadIdx.x;
#pragma unroll
  for (int i = 0; i < 4; i++) {
    int idx4 = t + i * 256;  // 1024 float4 = 64 rows x 16 float4
    int r = idx4 >> 4, c4 = idx4 & 15;
    float4 v = *(const float4*)(W + (size_t)(k0 + r) * 768 + n0 + c4 * 4);
    T[r][c4 * 4 + 0] = v.x; T[r][c4 * 4 + 1] = v.y;
    T[r][c4 * 4 + 2] = v.z; T[r][c4 * 4 + 3] = v.w;
  }
  __syncthreads();
#pragma unroll
  for (int i = 0; i < 2; i++) {
    int ci = t + i * 256;  // 512 ushort8 chunks = 64 n-rows x 8
    int nl = ci >> 3, k8 = ci & 7;
    u16x8 o;
#pragma unroll
    for (int jj = 0; jj < 8; jj++) o[jj] = f2b(T[k8 * 8 + jj][nl]);
    *(u16x8*)(WT + ((size_t)mat * 768 + n0 + nl) * 768 + k0 + k8 * 8) = o;
  }
}

// ---------------------------------------------------------------------------
// bf16 MFMA GEMM (m97 structure): A[8192][768] bf16 x WT[nrows][768] bf16.
// 128x128 tile, BK=32, 4 waves (2x2 of 64x64), 16x16x32 MFMA,
// global_load_lds width-16 staging.
// MODE 0: 30 n-blocks over 5 concatenated matrices; bf16 output scattered to
//         [B,H,S,HD] per-matrix buffers (stride QSZ), matrix 0 scaled 0.125.
// MODE 1: single matrix (Wo); fp32 output row-major [8192][768].
// ---------------------------------------------------------------------------
struct BiasArgs { const float* bias[5]; };

template <int MODE>
__global__ __launch_bounds__(256) void gemm_bf16(
    const u16* __restrict__ A, const u16* __restrict__ WT, BiasArgs ba,
    u16* __restrict__ outb, float* __restrict__ outf) {
  __shared__ __align__(16) u16 As[128 * 32];
  __shared__ __align__(16) u16 Bs[128 * 32];
  const int tid = threadIdx.x;
  const int w = tid >> 6, l = tid & 63;
  const int m0 = blockIdx.y * 128;
  const int wsel = (MODE == 0) ? ((int)blockIdx.x / 6) : 0;
  const int n0 =
      (MODE == 0) ? (((int)blockIdx.x % 6) * 128) : ((int)blockIdx.x * 128);
  const int nw0 = (int)blockIdx.x * 128;  // row base into WT
  const float* __restrict__ bias = ba.bias[wsel];
  const int wm = w >> 1, wn = w & 1;
  const int srow = l >> 2;
  const int skc = (l & 3) * 8;

  f32x4 acc[4][4];
#pragma unroll
  for (int i = 0; i < 4; i++)
#pragma unroll
    for (int j = 0; j < 4; j++)
      acc[i][j] = (f32x4){0.f, 0.f, 0.f, 0.f};

  for (int k0 = 0; k0 < 768; k0 += 32) {
    __syncthreads();
#pragma unroll
    for (int i = 0; i < 2; i++) {
      const int ci = i * 4 + w;
      load_lds16(A + (size_t)(m0 + ci * 16 + srow) * 768 + k0 + skc,
                 (char*)As + ci * 1024);
    }
#pragma unroll
    for (int i = 0; i < 2; i++) {
      const int ci = i * 4 + w;
      load_lds16(WT + (size_t)(nw0 + ci * 16 + srow) * 768 + k0 + skc,
                 (char*)Bs + ci * 1024);
    }
    asm volatile("s_waitcnt vmcnt(0)" ::: "memory");
    __syncthreads();
    s16x8 af[4], bf[4];
#pragma unroll
    for (int mi = 0; mi < 4; mi++)
      af[mi] = *(const s16x8*)(As + (wm * 64 + mi * 16 + (l & 15)) * 32 +
                               (l >> 4) * 8);
#pragma unroll
    for (int nj = 0; nj < 4; nj++)
      bf[nj] = *(const s16x8*)(Bs + (wn * 64 + nj * 16 + (l & 15)) * 32 +
                               (l >> 4) * 8);
#pragma unroll
    for (int mi = 0; mi < 4; mi++)
#pragma unroll
      for (int nj = 0; nj < 4; nj++)
        acc[mi][nj] = __builtin_amdgcn_mfma_f32_16x16x32_bf16(
            af[mi], bf[nj], acc[mi][nj], 0, 0, 0);
  }

  const int rbase = (l >> 4) * 4;
  const int cl = l & 15;
  if (MODE == 0) {
    const float scale = (wsel == 0) ? 0.125f : 1.0f;
    u16* outw = outb + (size_t)wsel * ((size_t)BB * HH * SS * HDD);
#pragma unroll
    for (int nj = 0; nj < 4; nj++) {
      const int c = n0 + wn * 64 + nj * 16 + cl;
      const float bv = bias[c];
      const int h = c >> 6, hd = c & 63;
#pragma unroll
      for (int mi = 0; mi < 4; mi++) {
#pragma unroll
        for (int r = 0; r < 4; r++) {
          const int m = m0 + wm * 64 + mi * 16 + rbase + r;
          const int b = m >> 12, s = m & 4095;
          outw[((size_t)(b * HH + h) * SS + s) * HDD + hd] =
              f2b((acc[mi][nj][r] + bv) * scale);
        }
      }
    }
  } else {
#pragma unroll
    for (int nj = 0; nj < 4; nj++) {
      const int c = n0 + wn * 64 + nj * 16 + cl;
      const float bv = bias[c];
#pragma unroll
      for (int mi = 0; mi < 4; mi++) {
#pragma unroll
        for (int r = 0; r < 4; r++) {
          const int m = m0 + wm * 64 + mi * 16 + rbase + r;
          outf[(size_t)m * 768 + c] = acc[mi][nj][r] + bv;
        }
      }
    }
  }
}

// ---------------------------------------------------------------------------
// Banded sliding-window attention + global-key columns (bf16 Q/K/V in,
// bf16 ATT out; fp32 internal math). One WG = 64 queries x 4 dim-slices.
// ---------------------------------------------------------------------------
__global__ __launch_bounds__(256) void band_attn(
    const u16* __restrict__ Q, const u16* __restrict__ K,
    const u16* __restrict__ V, const int* __restrict__ amask,
    u16* __restrict__ ATT) {
  const int sub = blockIdx.x & 3;
  const int c = blockIdx.x >> 2;
  const int h = blockIdx.y;
  const int b = blockIdx.z;
  const int t = threadIdx.x;
  const int qi = t >> 2;
  const int sl = t & 3;
  const int q0 = c * W1C + sub * 64;
  const int q_abs = q0 + qi;
  const size_t bh = (size_t)(b * HH + h) * SS;

  __shared__ float Kl[64 * 64];
  __shared__ float Vl[64 * 64];
  __shared__ int Ml[64];

  float q[16];
  {
    u16x8 a = *(const u16x8*)(Q + (bh + q_abs) * 64 + sl * 16);
    u16x8 bq8 = *(const u16x8*)(Q + (bh + q_abs) * 64 + sl * 16 + 8);
#pragma unroll
    for (int e = 0; e < 8; e++) { q[e] = b2f(a[e]); q[8 + e] = b2f(bq8[e]); }
  }
  float acc[16];
#pragma unroll
  for (int d = 0; d < 16; d++) acc[d] = 0.f;
  float denom = 0.f;

  // ---- global-key columns ----
#pragma unroll
  for (int j = 0; j < GG; j++) {
    float kd[16];
    {
      u16x8 a = *(const u16x8*)(K + (bh + j) * 64 + sl * 16);
      u16x8 b8 = *(const u16x8*)(K + (bh + j) * 64 + sl * 16 + 8);
#pragma unroll
      for (int e = 0; e < 8; e++) { kd[e] = b2f(a[e]); kd[8 + e] = b2f(b8[e]); }
    }
    float s = 0.f;
#pragma unroll
    for (int d = 0; d < 16; d++) s = fmaf(q[d], kd[d], s);
    s += __shfl_xor(s, 1);
    s += __shfl_xor(s, 2);
    float p = (amask[b * SS + j] >= 0) ? __expf(s) : 0.f;
    denom += p;
    u16x8 a = *(const u16x8*)(V + (bh + j) * 64 + sl * 16);
    u16x8 b8 = *(const u16x8*)(V + (bh + j) * 64 + sl * 16 + 8);
#pragma unroll
    for (int e = 0; e < 8; e++) {
      acc[e] = fmaf(p, b2f(a[e]), acc[e]);
      acc[8 + e] = fmaf(p, b2f(b8[e]), acc[8 + e]);
    }
  }

  // ---- banded window: 9 tiles of 64 keys ----
  for (int kt = 0; kt < 9; kt++) {
    const int j0 = q0 - W1C + kt * 64;
#pragma unroll
    for (int i = 0; i < 2; i++) {
      int ci = t + i * 256;  // 512 chunks of 8 elems
      int row = ci >> 3, c8 = ci & 7;
      int j = j0 + row;
      float kf[8], vf[8];
      if ((unsigned)j < (unsigned)SS) {
        u16x8 kv = *(const u16x8*)(K + (bh + j) * 64 + c8 * 8);
        u16x8 vv = *(const u16x8*)(V + (bh + j) * 64 + c8 * 8);
#pragma unroll
        for (int e = 0; e < 8; e++) { kf[e] = b2f(kv[e]); vf[e] = b2f(vv[e]); }
      } else {
#pragma unroll
        for (int e = 0; e < 8; e++) { kf[e] = 0.f; vf[e] = 0.f; }
      }
#pragma unroll
      for (int e = 0; e < 8; e++) {
        Kl[row * 64 + c8 * 8 + e] = kf[e];
        Vl[row * 64 + c8 * 8 + e] = vf[e];
      }
    }
    if (t < 64) {
      int j = j0 + t;
      Ml[t] = ((unsigned)j < (unsigned)SS) ? amask[b * SS + j] : -1;
    }
    __syncthreads();

    for (int kk = 0; kk < 64; kk++) {
      const int j = j0 + kk;
      const float4* kr = (const float4*)&Kl[kk * 64 + sl * 16];
      float s0 = 0.f, s1 = 0.f, s2 = 0.f, s3 = 0.f;
#pragma unroll
      for (int d4 = 0; d4 < 4; d4++) {
        float4 kv = kr[d4];
        s0 = fmaf(q[d4 * 4 + 0], kv.x, s0);
        s1 = fmaf(q[d4 * 4 + 1], kv.y, s1);
        s2 = fmaf(q[d4 * 4 + 2], kv.z, s2);
        s3 = fmaf(q[d4 * 4 + 3], kv.w, s3);
      }
      float s = (s0 + s1) + (s2 + s3);
      s += __shfl_xor(s, 1);
      s += __shfl_xor(s, 2);
      const int dd = j - q_abs;
      const bool ok = (dd >= -W1C) && (dd <= W1C) &&
                      ((unsigned)j < (unsigned)SS) && (Ml[kk] >= 0);
      float p = ok ? __expf(s) : 0.f;
      denom += p;
      const float4* vr = (const float4*)&Vl[kk * 64 + sl * 16];
#pragma unroll
      for (int d4 = 0; d4 < 4; d4++) {
        float4 vv = vr[d4];
        acc[d4 * 4 + 0] = fmaf(p, vv.x, acc[d4 * 4 + 0]);
        acc[d4 * 4 + 1] = fmaf(p, vv.y, acc[d4 * 4 + 1]);
        acc[d4 * 4 + 2] = fmaf(p, vv.z, acc[d4 * 4 + 2]);
        acc[d4 * 4 + 3] = fmaf(p, vv.w, acc[d4 * 4 + 3]);
      }
    }
    __syncthreads();
  }

  const float rowscale =
      (amask[b * SS + q_abs] >= 0) ? (1.0f / denom) : 0.f;
  u16* orow = ATT + ((size_t)b * SS + q_abs) * DD + h * 64 + sl * 16;
  u16x8 o0, o1;
#pragma unroll
  for (int e = 0; e < 8; e++) {
    o0[e] = f2b(acc[e] * rowscale);
    o1[e] = f2b(acc[8 + e] * rowscale);
  }
  *(u16x8*)orow = o0;
  *(u16x8*)(orow + 8) = o1;
}

// ---------------------------------------------------------------------------
// Global-token attention: one wave per (b,h,qi); bf16 KG/VG.
// ---------------------------------------------------------------------------
__global__ __launch_bounds__(64) void global_attn(
    const float* __restrict__ hs, const int* __restrict__ amask,
    const float* __restrict__ Wqg, const float* __restrict__ bqg,
    const u16* __restrict__ KG, const u16* __restrict__ VG,
    float* __restrict__ OG) {
  const int l = threadIdx.x;
  const int id = blockIdx.x;  // B*H*G = 192
  const int qi = id & 7;
  const int h = (id >> 3) % HH;
  const int b = id / (HH * GG);

  __shared__ float qrow[64];
  __shared__ float red[64 * 65];

  float aq = bqg[h * 64 + l];
  const float* hsrow = hs + ((size_t)b * SS + qi) * DD;
  for (int t = 0; t < DD; t++)
    aq = fmaf(hsrow[t], Wqg[(size_t)t * DD + h * 64 + l], aq);
  qrow[l] = aq * 0.125f;
  __syncthreads();

  float q[64];
#pragma unroll
  for (int d = 0; d < 64; d++) q[d] = qrow[d];

  float accv[64];
#pragma unroll
  for (int d = 0; d < 64; d++) accv[d] = 0.f;
  float denom = 0.f;

  const u16* kbase = KG + ((size_t)(b * HH + h)) * SS * 64;
  const u16* vbase = VG + ((size_t)(b * HH + h)) * SS * 64;
  for (int t = 0; t < 64; t++) {
    const int j = l + t * 64;
    const u16x8* kr = (const u16x8*)(kbase + (size_t)j * 64);
    float s = 0.f;
#pragma unroll
    for (int d8 = 0; d8 < 8; d8++) {
      u16x8 kv = kr[d8];
#pragma unroll
      for (int e = 0; e < 8; e++) s = fmaf(q[d8 * 8 + e], b2f(kv[e]), s);
    }
    float p = (amask[b * SS + j] >= 0) ? __expf(s) : 0.f;
    denom += p;
    const u16x8* vr = (const u16x8*)(vbase + (size_t)j * 64);
#pragma unroll
    for (int d8 = 0; d8 < 8; d8++) {
      u16x8 vv = vr[d8];
#pragma unroll
      for (int e = 0; e < 8; e++)
        accv[d8 * 8 + e] = fmaf(p, b2f(vv[e]), accv[d8 * 8 + e]);
    }
  }

#pragma unroll
  for (int d = 0; d < 64; d++) red[l * 65 + d] = accv[d];
  red[l * 65 + 64] = denom;
  __syncthreads();

  float od = 0.f, dsum = 0.f;
  for (int t = 0; t < 64; t++) {
    od += red[t * 65 + l];
    dsum += red[t * 65 + 64];
  }
  OG[(((size_t)(b * HH + h)) * GG + qi) * 64 + l] = od / dsum;
}

// ---------------------------------------------------------------------------
// Copy OG into ATT rows s < G (bf16 merged layout).
// ---------------------------------------------------------------------------
__global__ __launch_bounds__(256) void merge_og(const float* __restrict__ OG,
                                                u16* __restrict__ ATT) {
  int i = blockIdx.x * 256 + threadIdx.x;  // B*G*D = 12288
  if (i >= BB * GG * DD) return;
  int d = i % DD;
  int qi = (i / DD) % GG;
  int b = i / (DD * GG);
  int h = d >> 6, hd = d & 63;
  ATT[((size_t)b * SS + qi) * DD + d] =
      f2b(OG[(((size_t)(b * HH + h)) * GG + qi) * 64 + hd]);
}

// ---------------------------------------------------------------------------
extern "C" void kernel_launch(void* const* d_in, const int* in_sizes, int n_in,
                              void* d_out, int out_size, void* d_ws,
                              size_t ws_size, hipStream_t stream) {
  const float* hs = (const float*)d_in[0];
  const int* amask = (const int*)d_in[1];
  const float* Wq = (const float*)d_in[2];
  const float* bq = (const float*)d_in[3];
  const float* Wk = (const float*)d_in[4];
  const float* bk = (const float*)d_in[5];
  const float* Wv = (const float*)d_in[6];
  const float* bv = (const float*)d_in[7];
  const float* Wqg = (const float*)d_in[8];
  const float* bqg = (const float*)d_in[9];
  const float* Wkg = (const float*)d_in[10];
  const float* bkg = (const float*)d_in[11];
  const float* Wvg = (const float*)d_in[12];
  const float* bvg = (const float*)d_in[13];
  const float* Wo = (const float*)d_in[14];
  const float* bo = (const float*)d_in[15];
  float* out = (float*)d_out;

  char* ws = (char*)d_ws;
  const size_t QSZB = (size_t)BB * HH * SS * HDD * 2;  // 12582912 B
  u16* Qb = (u16*)(ws + 0);
  u16* Kb = (u16*)(ws + QSZB);
  u16* Vb = (u16*)(ws + 2 * QSZB);
  u16* KGb = (u16*)(ws + 3 * QSZB);
  u16* VGb = (u16*)(ws + 4 * QSZB);
  float* OGf = (float*)(ws + 5 * QSZB);          // 49152 B
  u16* Ab = (u16*)(ws + 5 * QSZB + 49152);       // 12582912 B
  u16* WTb = (u16*)(ws + 5 * QSZB + 49152 + QSZB);            // 7077888 B
  u16* ATTb = (u16*)(ws + 5 * QSZB + 49152 + QSZB + 7077888);

  // 1) convert hs -> bf16 A
  hipLaunchKernelGGL(cvt_f32_bf16, dim3(3072), dim3(256), 0, stream, hs, Ab,
                     (int)((size_t)BB * SS * DD / 8));

  // 2) transpose+convert 6 weight matrices -> WT[mat][n][k] bf16
  WtArgs wa;
  wa.W[0] = Wq; wa.W[1] = Wk; wa.W[2] = Wv;
  wa.W[3] = Wkg; wa.W[4] = Wvg; wa.W[5] = Wo;
  hipLaunchKernelGGL(transpose_wt, dim3(12, 12, 6), dim3(256), 0, stream, wa,
                     WTb);

  // 3) fused projections (bf16 MFMA): Q,K,V,KG,VG
  BiasArgs b0;
  b0.bias[0] = bq; b0.bias[1] = bk; b0.bias[2] = bv;
  b0.bias[3] = bkg; b0.bias[4] = bvg;
  hipLaunchKernelGGL((gemm_bf16<0>), dim3(30, 64), dim3(256), 0, stream, Ab,
                     WTb, b0, Qb, (float*)nullptr);

  // 4) global-token attention -> OG (fp32)
  hipLaunchKernelGGL(global_attn, dim3(192), dim3(64), 0, stream, hs, amask,
                     Wqg, bqg, KGb, VGb, OGf);

  // 5) banded attention -> ATT (bf16)
  hipLaunchKernelGGL(band_attn, dim3(NCC * 4, HH, BB), dim3(256), 0, stream,
                     Qb, Kb, Vb, amask, ATTb);

  // 6) merge global-token rows into ATT
  hipLaunchKernelGGL(merge_og, dim3(48), dim3(256), 0, stream, OGf, ATTb);

  // 7) output projection (bf16 MFMA, fp32 out)
  BiasArgs b1;
  for (int i = 0; i < 5; i++) b1.bias[i] = bo;
  hipLaunchKernelGGL((gemm_bf16<1>), dim3(6, 64), dim3(256), 0, stream, ATTb,
                     WTb + (size_t)5 * 768 * 768, b1, (u16*)nullptr, out);
}

// Round 4
// 213.200 us; speedup vs baseline: 7.0908x; 3.0345x over previous
//
#include <hip/hip_runtime.h>

#define BB 2
#define SS 4096
#define DD 768
#define HH 12
#define HDD 64
#define W1C 256
#define NCC 16
#define GG 8

typedef unsigned short u16;
typedef __attribute__((ext_vector_type(4))) unsigned short u16x4;
typedef __attribute__((ext_vector_type(8))) unsigned short u16x8;
typedef __attribute__((ext_vector_type(8))) short s16x8;
typedef __attribute__((ext_vector_type(4))) float f32x4;

__device__ __forceinline__ float b2f(u16 u) {
  union { unsigned int i; float f; } v;
  v.i = ((unsigned int)u) << 16;
  return v.f;
}
__device__ __forceinline__ u16 f2b(float f) {
  union { float f; unsigned int i; } v;
  v.f = f;
  unsigned int r = v.i + 0x7FFFu + ((v.i >> 16) & 1u);
  return (u16)(r >> 16);
}
__device__ __forceinline__ float fexp2(float x) {
#if __has_builtin(__builtin_amdgcn_exp2f)
  return __builtin_amdgcn_exp2f(x);
#else
  return exp2f(x);
#endif
}
__device__ __forceinline__ unsigned pk_bf16(float lo, float hi) {
  unsigned r;
  asm("v_cvt_pk_bf16_f32 %0, %1, %2" : "=v"(r) : "v"(lo), "v"(hi));
  return r;
}
__device__ __forceinline__ void load_lds16(const void* g, void* l) {
  __builtin_amdgcn_global_load_lds(
      (const __attribute__((address_space(1))) unsigned int*)g,
      (__attribute__((address_space(3))) unsigned int*)l, 16, 0, 0);
}

#define QSCALE 0.18033688011112042f  // 0.125 * log2(e)

// ---------------------------------------------------------------------------
// fp32 -> bf16 bulk convert (8 elems/thread)
// ---------------------------------------------------------------------------
__global__ __launch_bounds__(256) void cvt_f32_bf16(
    const float* __restrict__ in, u16* __restrict__ out, int n8) {
  int i = blockIdx.x * 256 + threadIdx.x;
  if (i >= n8) return;
  const float4* p = (const float4*)(in + (size_t)i * 8);
  float4 a = p[0], b = p[1];
  u16x8 o;
  o[0] = f2b(a.x); o[1] = f2b(a.y); o[2] = f2b(a.z); o[3] = f2b(a.w);
  o[4] = f2b(b.x); o[5] = f2b(b.y); o[6] = f2b(b.z); o[7] = f2b(b.w);
  *(u16x8*)(out + (size_t)i * 8) = o;
}

// ---------------------------------------------------------------------------
// Transpose + convert 6 weight matrices [768][768] fp32 (W[k][n]) into
// WT[mat][n][k] bf16. 64x64 LDS tiles.
// ---------------------------------------------------------------------------
struct WtArgs { const float* W[6]; };

__global__ __launch_bounds__(256) void transpose_wt(WtArgs wa,
                                                    u16* __restrict__ WT) {
  __shared__ float T[64][65];
  const int mat = blockIdx.z;
  const int k0 = blockIdx.y * 64;
  const int n0 = blockIdx.x * 64;
  const float* __restrict__ W = wa.W[mat];
  const int t = threadIdx.x;
#pragma unroll
  for (int i = 0; i < 4; i++) {
    int idx4 = t + i * 256;
    int r = idx4 >> 4, c4 = idx4 & 15;
    float4 v = *(const float4*)(W + (size_t)(k0 + r) * 768 + n0 + c4 * 4);
    T[r][c4 * 4 + 0] = v.x; T[r][c4 * 4 + 1] = v.y;
    T[r][c4 * 4 + 2] = v.z; T[r][c4 * 4 + 3] = v.w;
  }
  __syncthreads();
#pragma unroll
  for (int i = 0; i < 2; i++) {
    int ci = t + i * 256;
    int nl = ci >> 3, k8 = ci & 7;
    u16x8 o;
#pragma unroll
    for (int jj = 0; jj < 8; jj++) o[jj] = f2b(T[k8 * 8 + jj][nl]);
    *(u16x8*)(WT + ((size_t)mat * 768 + n0 + nl) * 768 + k0 + k8 * 8) = o;
  }
}

// ---------------------------------------------------------------------------
// bf16 MFMA GEMM (m97 structure). MODE 0: 5 concat matrices, bf16 out
// scattered to [B,H,S,HD] buffers (matrix 0 = Q, scaled 0.125*log2e).
// MODE 1: Wo, fp32 out row-major.
// ---------------------------------------------------------------------------
struct BiasArgs { const float* bias[5]; };

template <int MODE>
__global__ __launch_bounds__(256) void gemm_bf16(
    const u16* __restrict__ A, const u16* __restrict__ WT, BiasArgs ba,
    u16* __restrict__ outb, float* __restrict__ outf) {
  __shared__ __align__(16) u16 As[128 * 32];
  __shared__ __align__(16) u16 Bs[128 * 32];
  const int tid = threadIdx.x;
  const int w = tid >> 6, l = tid & 63;
  const int m0 = blockIdx.y * 128;
  const int wsel = (MODE == 0) ? ((int)blockIdx.x / 6) : 0;
  const int n0 =
      (MODE == 0) ? (((int)blockIdx.x % 6) * 128) : ((int)blockIdx.x * 128);
  const int nw0 = (int)blockIdx.x * 128;
  const float* __restrict__ bias = ba.bias[wsel];
  const int wm = w >> 1, wn = w & 1;
  const int srow = l >> 2;
  const int skc = (l & 3) * 8;

  f32x4 acc[4][4];
#pragma unroll
  for (int i = 0; i < 4; i++)
#pragma unroll
    for (int j = 0; j < 4; j++) acc[i][j] = (f32x4){0.f, 0.f, 0.f, 0.f};

  for (int k0 = 0; k0 < 768; k0 += 32) {
    __syncthreads();
#pragma unroll
    for (int i = 0; i < 2; i++) {
      const int ci = i * 4 + w;
      load_lds16(A + (size_t)(m0 + ci * 16 + srow) * 768 + k0 + skc,
                 (char*)As + ci * 1024);
    }
#pragma unroll
    for (int i = 0; i < 2; i++) {
      const int ci = i * 4 + w;
      load_lds16(WT + (size_t)(nw0 + ci * 16 + srow) * 768 + k0 + skc,
                 (char*)Bs + ci * 1024);
    }
    asm volatile("s_waitcnt vmcnt(0)" ::: "memory");
    __syncthreads();
    s16x8 af[4], bf[4];
#pragma unroll
    for (int mi = 0; mi < 4; mi++)
      af[mi] = *(const s16x8*)(As + (wm * 64 + mi * 16 + (l & 15)) * 32 +
                               (l >> 4) * 8);
#pragma unroll
    for (int nj = 0; nj < 4; nj++)
      bf[nj] = *(const s16x8*)(Bs + (wn * 64 + nj * 16 + (l & 15)) * 32 +
                               (l >> 4) * 8);
#pragma unroll
    for (int mi = 0; mi < 4; mi++)
#pragma unroll
      for (int nj = 0; nj < 4; nj++)
        acc[mi][nj] = __builtin_amdgcn_mfma_f32_16x16x32_bf16(
            af[mi], bf[nj], acc[mi][nj], 0, 0, 0);
  }

  const int rbase = (l >> 4) * 4;
  const int cl = l & 15;
  if (MODE == 0) {
    const float scale = (wsel == 0) ? QSCALE : 1.0f;
    u16* outw = outb + (size_t)wsel * ((size_t)BB * HH * SS * HDD);
#pragma unroll
    for (int nj = 0; nj < 4; nj++) {
      const int c = n0 + wn * 64 + nj * 16 + cl;
      const float bv = bias[c];
      const int h = c >> 6, hd = c & 63;
#pragma unroll
      for (int mi = 0; mi < 4; mi++) {
#pragma unroll
        for (int r = 0; r < 4; r++) {
          const int m = m0 + wm * 64 + mi * 16 + rbase + r;
          const int b = m >> 12, s = m & 4095;
          outw[((size_t)(b * HH + h) * SS + s) * HDD + hd] =
              f2b((acc[mi][nj][r] + bv) * scale);
        }
      }
    }
  } else {
#pragma unroll
    for (int nj = 0; nj < 4; nj++) {
      const int c = n0 + wn * 64 + nj * 16 + cl;
      const float bv = bias[c];
#pragma unroll
      for (int mi = 0; mi < 4; mi++) {
#pragma unroll
        for (int r = 0; r < 4; r++) {
          const int m = m0 + wm * 64 + mi * 16 + rbase + r;
          outf[(size_t)m * 768 + c] = acc[mi][nj][r] + bv;
        }
      }
    }
  }
}

// ---------------------------------------------------------------------------
// qg projection: QG[bh][qi][d] = (hs[b,qi,:] @ Wqg + bqg)[h*64+d] * QSCALE
// for qi<8; rows 8..15 zeroed. bf16 out. Grid = 24 (bh).
// ---------------------------------------------------------------------------
__global__ __launch_bounds__(256) void qg_proj(
    const float* __restrict__ hs, const float* __restrict__ Wqg,
    const float* __restrict__ bqg, u16* __restrict__ QG) {
  __shared__ float hsL[8][768];
  const int bh = blockIdx.x;
  const int b = bh / HH, h = bh % HH;
  const int t = threadIdx.x;
#pragma unroll
  for (int i = 0; i < 6; i++) {
    int idx = t + i * 256;  // 1536 float4 = 8 rows x 192
    int row = idx / 192, c4 = idx % 192;
    *(float4*)&hsL[row][c4 * 4] =
        *(const float4*)(hs + ((size_t)b * SS + row) * DD + c4 * 4);
  }
  __syncthreads();
#pragma unroll
  for (int rep = 0; rep < 2; rep++) {
    int qi = rep * 4 + (t >> 6);
    int d = t & 63, n = h * 64 + d;
    float acc = bqg[n];
    for (int k = 0; k < DD; k++)
      acc = fmaf(hsL[qi][k], Wqg[(size_t)k * DD + n], acc);
    QG[((size_t)bh * 16 + qi) * 64 + d] = f2b(acc * QSCALE);
  }
#pragma unroll
  for (int i = 0; i < 2; i++) {
    int idx = t + i * 256;
    int row = 8 + (idx >> 6), d = idx & 63;
    QG[((size_t)bh * 16 + row) * 64 + d] = 0;
  }
}

// ---------------------------------------------------------------------------
// MFMA attention. GLOBAL=0: banded sliding-window + global-key mini-tile,
// one WG = 64 queries of one (b,h); 10 key tiles of 64; writes normalized
// bf16 ATT [B,S,D]. GLOBAL=1: global tokens (16 padded queries) vs 512-key
// split; per-wave tiles; writes fp32 partials (num, den).
// Layouts: S^T = K*Q^T so q = lane&15 stays lane-local; PV as V^T*P^T.
// K and VT tiles XOR-swizzled (T2); K staged via global_load_lds with
// pre-swizzled source (m173).
// ---------------------------------------------------------------------------
template <int GLOBAL>
__global__ __launch_bounds__(256) void attn_mfma(
    const u16* __restrict__ Q, const u16* __restrict__ K,
    const u16* __restrict__ V, const int* __restrict__ amask,
    u16* __restrict__ ATT, float* __restrict__ Pnum,
    float* __restrict__ Pden) {
  extern __shared__ __align__(16) char smem[];
  const int tid = threadIdx.x;
  const int w = tid >> 6, lane = tid & 63;
  const int lq = lane & 15, g = lane >> 4;
  const int h = blockIdx.y, b = blockIdx.z;
  const int bh = b * HH + h;
  const size_t bhs = (size_t)bh * SS;
  const int q0 = GLOBAL ? 0 : (int)blockIdx.x * 64;
  const int split = GLOBAL ? (int)blockIdx.x : 0;

  char* Kl;
  char* VT;
  if constexpr (GLOBAL) {
    Kl = smem + w * 16384;
    VT = Kl + 8192;
  } else {
    Kl = smem;
    VT = smem + 8192;
  }

  // Q fragments (held in registers for the whole kernel)
  s16x8 qf[2];
  {
    const u16* qp = GLOBAL ? (Q + ((size_t)bh * 16 + lq) * 64)
                           : (Q + (bhs + q0 + w * 16 + lq) * 64);
    qf[0] = *(const s16x8*)(qp + g * 8);
    qf[1] = *(const s16x8*)(qp + 32 + g * 8);
  }

  f32x4 oacc[4];
#pragma unroll
  for (int i = 0; i < 4; i++) oacc[i] = (f32x4){0.f, 0.f, 0.f, 0.f};
  float denom = 0.f;

  const int NT = GLOBAL ? 2 : 10;
  for (int kt = 0; kt < NT; kt++) {
    int j0, klimit;
    bool bandfree;
    if constexpr (GLOBAL) {
      j0 = split * 512 + (w * 2 + kt) * 64;
      bandfree = true;
      klimit = 64;
    } else {
      if (kt < 9) { j0 = q0 - 256 + kt * 64; bandfree = false; klimit = 64; }
      else        { j0 = 0;                  bandfree = true;  klimit = 8; }
    }

    // key-validity ballot (lane <-> key index)
    int jm = j0 + lane;
    int mv = ((unsigned)jm < (unsigned)SS) ? amask[b * SS + jm] : -1;
    bool okk = (mv >= 0) && (lane < klimit);
    unsigned long long vm = __ballot(okk);

    // ---- staging ----
    if constexpr (GLOBAL) {
      asm volatile("s_waitcnt lgkmcnt(0)" ::: "memory");
      const u16* Ks = K + bhs * 64 + (size_t)j0 * 64;
#pragma unroll
      for (int i = 0; i < 8; i++) {
        int ci = i * 64 + lane;
        int row = ci >> 3, cc = ci & 7, cs = cc ^ (row & 7);
        load_lds16(Ks + row * 64 + cs * 8, Kl + i * 1024);
      }
      const u16* Vs = V + bhs * 64 + (size_t)j0 * 64;
#pragma unroll
      for (int p = 0; p < 8; p++) {
        u16x8 vv = *(const u16x8*)(Vs + (size_t)lane * 64 + p * 8);
#pragma unroll
        for (int e = 0; e < 8; e++)
          *(u16*)(VT + (p * 8 + e) * 128 + ((lane * 2) ^ (e << 4))) = vv[e];
      }
      asm volatile("s_waitcnt vmcnt(0) lgkmcnt(0)" ::: "memory");
    } else {
      __syncthreads();  // previous tile's readers done
      if (j0 >= 0 && j0 + 64 <= SS) {
        const u16* Ks = K + bhs * 64 + (size_t)j0 * 64;
#pragma unroll
        for (int i = 0; i < 2; i++) {
          int ci = (i * 4 + w) * 64 + lane;
          int row = ci >> 3, cc = ci & 7, cs = cc ^ (row & 7);
          load_lds16(Ks + row * 64 + cs * 8, Kl + (i * 4 + w) * 1024);
        }
      } else {
#pragma unroll
        for (int i = 0; i < 2; i++) {
          int ci = (i * 4 + w) * 64 + lane;
          int row = ci >> 3, cc = ci & 7, cs = cc ^ (row & 7);
          int jj = j0 + row;
          u16x8 val;
#pragma unroll
          for (int e = 0; e < 8; e++) val[e] = 0;
          if ((unsigned)jj < (unsigned)SS)
            val = *(const u16x8*)(K + (bhs + jj) * 64 + cs * 8);
          *(u16x8*)(Kl + ci * 16) = val;
        }
      }
#pragma unroll
      for (int p = 0; p < 2; p++) {
        int d0 = p * 32 + w * 8;
        int jj = j0 + lane;
        u16x8 vv;
#pragma unroll
        for (int e = 0; e < 8; e++) vv[e] = 0;
        if ((unsigned)jj < (unsigned)SS)
          vv = *(const u16x8*)(V + (bhs + jj) * 64 + d0);
#pragma unroll
        for (int e = 0; e < 8; e++)
          *(u16*)(VT + (d0 + e) * 128 + ((lane * 2) ^ (e << 4))) = vv[e];
      }
      asm volatile("s_waitcnt vmcnt(0)" ::: "memory");
      __syncthreads();
    }

    // ---- QK^T: S^T[k][q], lane: q=lq, k = ks*16 + g*4 + r ----
    f32x4 sc[4];
#pragma unroll
    for (int i = 0; i < 4; i++) sc[i] = (f32x4){0.f, 0.f, 0.f, 0.f};
#pragma unroll
    for (int s = 0; s < 2; s++) {
#pragma unroll
      for (int ks = 0; ks < 4; ks++) {
        s16x8 kf = *(const s16x8*)(Kl + (ks * 16 + lq) * 128 +
                                   (((s * 4 + g) ^ (lq & 7)) << 4));
        sc[ks] = __builtin_amdgcn_mfma_f32_16x16x32_bf16(kf, qf[s], sc[ks],
                                                          0, 0, 0);
      }
    }

    // ---- mask + exp2 -> P (reuse sc), accumulate denom ----
    {
      const unsigned mlo = (unsigned)vm, mhi = (unsigned)(vm >> 32);
      const int q_abs = q0 + w * 16 + lq;
      bool allin = bandfree;
      if constexpr (!GLOBAL) {
        const int qw = q0 + w * 16;
        allin = bandfree || (j0 >= qw - 241 && j0 <= qw + 193);
      }
      const bool fast = (vm == ~0ull) && allin;
      const int ddq = j0 + g * 4 - q_abs;
      const int gsh = g * 4;
      if (fast) {
#pragma unroll
        for (int ks = 0; ks < 4; ks++)
#pragma unroll
          for (int r = 0; r < 4; r++) {
            float p = fexp2(sc[ks][r]);
            sc[ks][r] = p;
            denom += p;
          }
      } else {
#pragma unroll
        for (int ks = 0; ks < 4; ks++)
#pragma unroll
          for (int r = 0; r < 4; r++) {
            float e = fexp2(sc[ks][r]);
            unsigned bit =
                ((ks < 2 ? mlo : mhi) >> (gsh + ((ks & 1) * 16 + r))) & 1u;
            bool ok = bit && (allin ||
                              (unsigned)(ddq + ks * 16 + r + 256) <= 512u);
            float p = ok ? e : 0.f;
            sc[ks][r] = p;
            denom += p;
          }
      }
    }

    // ---- P^T B-fragments (shfl + cvt_pk) and PV: oacc^T += V^T * P^T ----
#pragma unroll
    for (int s = 0; s < 2; s++) {
      const int srcA = lq + ((g & 1) << 5);
      const bool hiSel = g >= 2;
      float L[4], H[4];
#pragma unroll
      for (int r = 0; r < 4; r++) {
        float a0 = __shfl(sc[2 * s][r], srcA);
        float a1 = __shfl(sc[2 * s + 1][r], srcA);
        L[r] = hiSel ? a1 : a0;
        float b0 = __shfl(sc[2 * s][r], srcA + 16);
        float b1 = __shfl(sc[2 * s + 1][r], srcA + 16);
        H[r] = hiSel ? b1 : b0;
      }
      union { unsigned u[4]; s16x8 v; } pf;
      pf.u[0] = pk_bf16(L[0], L[1]);
      pf.u[1] = pk_bf16(L[2], L[3]);
      pf.u[2] = pk_bf16(H[0], H[1]);
      pf.u[3] = pk_bf16(H[2], H[3]);
#pragma unroll
      for (int dblk = 0; dblk < 4; dblk++) {
        s16x8 vf = *(const s16x8*)(VT + (dblk * 16 + lq) * 128 +
                                   (((s * 4 + g) ^ (lq & 7)) << 4));
        oacc[dblk] = __builtin_amdgcn_mfma_f32_16x16x32_bf16(vf, pf.v,
                                                              oacc[dblk],
                                                              0, 0, 0);
      }
    }
  }  // tiles

  // ---- epilogue ----
  denom += __shfl_xor(denom, 16);
  denom += __shfl_xor(denom, 32);
  if constexpr (!GLOBAL) {
    const int q_abs = q0 + w * 16 + lq;
    const float rowscale = (amask[b * SS + q_abs] >= 0) ? (1.f / denom) : 0.f;
    u16* orow = ATT + ((size_t)b * SS + q_abs) * DD + h * 64;
#pragma unroll
    for (int dblk = 0; dblk < 4; dblk++) {
      u16x4 o;
#pragma unroll
      for (int r = 0; r < 4; r++) o[r] = f2b(oacc[dblk][r] * rowscale);
      *(u16x4*)(orow + dblk * 16 + g * 4) = o;
    }
  } else {
    const int pidx = split * 4 + w;
    float* np = Pnum + ((size_t)bh * 32 + pidx) * 1024;
#pragma unroll
    for (int dblk = 0; dblk < 4; dblk++)
#pragma unroll
      for (int r = 0; r < 4; r++)
        np[(dblk * 16 + g * 4 + r) * 16 + lq] = oacc[dblk][r];
    Pden[((size_t)bh * 32 + pidx) * 16 + lq] = denom;
  }
}

// ---------------------------------------------------------------------------
// Merge global-token partials and overwrite ATT rows < G.
// Grid = 24 (bh), block = 512 (q=t>>6 in 0..7, d=t&63).
// ---------------------------------------------------------------------------
__global__ __launch_bounds__(512) void gmerge(const float* __restrict__ Pnum,
                                              const float* __restrict__ Pden,
                                              u16* __restrict__ ATT) {
  const int bh = blockIdx.x;
  const int b = bh / HH, h = bh % HH;
  const int t = threadIdx.x;
  const int q = t >> 6, d = t & 63;
  float num = 0.f, den = 0.f;
#pragma unroll 4
  for (int p = 0; p < 32; p++) {
    num += Pnum[((size_t)bh * 32 + p) * 1024 + d * 16 + q];
    den += Pden[((size_t)bh * 32 + p) * 16 + q];
  }
  ATT[((size_t)b * SS + q) * DD + h * 64 + d] = f2b(num / den);
}

// ---------------------------------------------------------------------------
extern "C" void kernel_launch(void* const* d_in, const int* in_sizes, int n_in,
                              void* d_out, int out_size, void* d_ws,
                              size_t ws_size, hipStream_t stream) {
  const float* hs = (const float*)d_in[0];
  const int* amask = (const int*)d_in[1];
  const float* Wq = (const float*)d_in[2];
  const float* bq = (const float*)d_in[3];
  const float* Wk = (const float*)d_in[4];
  const float* bk = (const float*)d_in[5];
  const float* Wv = (const float*)d_in[6];
  const float* bv = (const float*)d_in[7];
  const float* Wqg = (const float*)d_in[8];
  const float* bqg = (const float*)d_in[9];
  const float* Wkg = (const float*)d_in[10];
  const float* bkg = (const float*)d_in[11];
  const float* Wvg = (const float*)d_in[12];
  const float* bvg = (const float*)d_in[13];
  const float* Wo = (const float*)d_in[14];
  const float* bo = (const float*)d_in[15];
  float* out = (float*)d_out;

  char* ws = (char*)d_ws;
  const size_t QSZB = (size_t)BB * HH * SS * HDD * 2;  // 12582912 B
  u16* Qb = (u16*)(ws + 0);
  u16* Kb = (u16*)(ws + QSZB);
  u16* Vb = (u16*)(ws + 2 * QSZB);
  u16* KGb = (u16*)(ws + 3 * QSZB);
  u16* VGb = (u16*)(ws + 4 * QSZB);
  u16* Ab = (u16*)(ws + 5 * QSZB);
  u16* WTb = (u16*)(ws + 6 * QSZB);                     // 7077888 B
  u16* ATTb = (u16*)(ws + 6 * QSZB + 7077888);          // QSZB
  u16* QGb = (u16*)(ws + 7 * QSZB + 7077888);           // 49152 B
  float* Pnum = (float*)(ws + 7 * QSZB + 7077888 + 49152);   // 3145728 B
  float* Pden = (float*)(ws + 7 * QSZB + 7077888 + 49152 + 3145728);  // 49152

  // 1) convert hs -> bf16 A
  hipLaunchKernelGGL(cvt_f32_bf16, dim3(3072), dim3(256), 0, stream, hs, Ab,
                     (int)((size_t)BB * SS * DD / 8));

  // 2) transpose+convert 6 weight matrices -> WT[mat][n][k] bf16
  WtArgs wa;
  wa.W[0] = Wq; wa.W[1] = Wk; wa.W[2] = Wv;
  wa.W[3] = Wkg; wa.W[4] = Wvg; wa.W[5] = Wo;
  hipLaunchKernelGGL(transpose_wt, dim3(12, 12, 6), dim3(256), 0, stream, wa,
                     WTb);

  // 3) fused projections (bf16 MFMA): Q,K,V,KG,VG  (Q scaled 0.125*log2e)
  BiasArgs b0;
  b0.bias[0] = bq; b0.bias[1] = bk; b0.bias[2] = bv;
  b0.bias[3] = bkg; b0.bias[4] = bvg;
  hipLaunchKernelGGL((gemm_bf16<0>), dim3(30, 64), dim3(256), 0, stream, Ab,
                     WTb, b0, Qb, (float*)nullptr);

  // 4) qg projection -> QGb
  hipLaunchKernelGGL(qg_proj, dim3(24), dim3(256), 0, stream, hs, Wqg, bqg,
                     QGb);

  // 5) global-token attention partials (reads KGb/VGb/QGb)
  hipLaunchKernelGGL((attn_mfma<1>), dim3(8, HH, BB), dim3(256), 65536,
                     stream, QGb, KGb, VGb, amask, (u16*)nullptr, Pnum, Pden);

  // 6) banded attention -> ATT (bf16)
  hipLaunchKernelGGL((attn_mfma<0>), dim3(64, HH, BB), dim3(256), 16384,
                     stream, Qb, Kb, Vb, amask, ATTb, (float*)nullptr,
                     (float*)nullptr);

  // 7) merge global-token rows into ATT
  hipLaunchKernelGGL(gmerge, dim3(24), dim3(512), 0, stream, Pnum, Pden, ATTb);

  // 8) output projection (bf16 MFMA, fp32 out)
  BiasArgs b1;
  for (int i = 0; i < 5; i++) b1.bias[i] = bo;
  hipLaunchKernelGGL((gemm_bf16<1>), dim3(6, 64), dim3(256), 0, stream, ATTb,
                     WTb + (size_t)5 * 768 * 768, b1, (u16*)nullptr, out);
}

// Round 5
// 208.911 us; speedup vs baseline: 7.2363x; 1.0205x over previous
//
#include <hip/hip_runtime.h>

#define BB 2
#define SS 4096
#define DD 768
#define HH 12
#define HDD 64
#define W1C 256
#define NCC 16
#define GG 8

typedef unsigned short u16;
typedef __attribute__((ext_vector_type(4))) unsigned short u16x4;
typedef __attribute__((ext_vector_type(8))) unsigned short u16x8;
typedef __attribute__((ext_vector_type(8))) short s16x8;
typedef __attribute__((ext_vector_type(4))) float f32x4;

__device__ __forceinline__ float b2f(u16 u) {
  union { unsigned int i; float f; } v;
  v.i = ((unsigned int)u) << 16;
  return v.f;
}
__device__ __forceinline__ u16 f2b(float f) {
  union { float f; unsigned int i; } v;
  v.f = f;
  unsigned int r = v.i + 0x7FFFu + ((v.i >> 16) & 1u);
  return (u16)(r >> 16);
}
__device__ __forceinline__ float fexp2(float x) {
#if __has_builtin(__builtin_amdgcn_exp2f)
  return __builtin_amdgcn_exp2f(x);
#else
  return exp2f(x);
#endif
}
__device__ __forceinline__ unsigned pk_bf16(float lo, float hi) {
  unsigned r;
  asm("v_cvt_pk_bf16_f32 %0, %1, %2" : "=v"(r) : "v"(lo), "v"(hi));
  return r;
}
__device__ __forceinline__ void load_lds16(const void* g, void* l) {
  __builtin_amdgcn_global_load_lds(
      (const __attribute__((address_space(1))) unsigned int*)g,
      (__attribute__((address_space(3))) unsigned int*)l, 16, 0, 0);
}

#define QSCALE 0.18033688011112042f  // 0.125 * log2(e)

// ---------------------------------------------------------------------------
// fp32 -> bf16 bulk convert (8 elems/thread)
// ---------------------------------------------------------------------------
__global__ __launch_bounds__(256) void cvt_f32_bf16(
    const float* __restrict__ in, u16* __restrict__ out, int n8) {
  int i = blockIdx.x * 256 + threadIdx.x;
  if (i >= n8) return;
  const float4* p = (const float4*)(in + (size_t)i * 8);
  float4 a = p[0], b = p[1];
  u16x8 o;
  o[0] = f2b(a.x); o[1] = f2b(a.y); o[2] = f2b(a.z); o[3] = f2b(a.w);
  o[4] = f2b(b.x); o[5] = f2b(b.y); o[6] = f2b(b.z); o[7] = f2b(b.w);
  *(u16x8*)(out + (size_t)i * 8) = o;
}

// ---------------------------------------------------------------------------
// Transpose + convert 6 weight matrices [768][768] fp32 (W[k][n]) into
// WT[mat][n][k] bf16. 64x64 LDS tiles.
// ---------------------------------------------------------------------------
struct WtArgs { const float* W[6]; };

__global__ __launch_bounds__(256) void transpose_wt(WtArgs wa,
                                                    u16* __restrict__ WT) {
  __shared__ float T[64][65];
  const int mat = blockIdx.z;
  const int k0 = blockIdx.y * 64;
  const int n0 = blockIdx.x * 64;
  const float* __restrict__ W = wa.W[mat];
  const int t = threadIdx.x;
#pragma unroll
  for (int i = 0; i < 4; i++) {
    int idx4 = t + i * 256;
    int r = idx4 >> 4, c4 = idx4 & 15;
    float4 v = *(const float4*)(W + (size_t)(k0 + r) * 768 + n0 + c4 * 4);
    T[r][c4 * 4 + 0] = v.x; T[r][c4 * 4 + 1] = v.y;
    T[r][c4 * 4 + 2] = v.z; T[r][c4 * 4 + 3] = v.w;
  }
  __syncthreads();
#pragma unroll
  for (int i = 0; i < 2; i++) {
    int ci = t + i * 256;
    int nl = ci >> 3, k8 = ci & 7;
    u16x8 o;
#pragma unroll
    for (int jj = 0; jj < 8; jj++) o[jj] = f2b(T[k8 * 8 + jj][nl]);
    *(u16x8*)(WT + ((size_t)mat * 768 + n0 + nl) * 768 + k0 + k8 * 8) = o;
  }
}

// ---------------------------------------------------------------------------
// bf16 MFMA GEMM. 128x128 tile, BK=64, XOR-swizzled LDS (T2: inverse-swizzled
// global source for global_load_lds + swizzled ds_read_b128 -> 2 lanes/bank),
// bijective XCD grid swizzle (T1).
// MODE 0: 5 concat matrices (grid 1920), bf16 out scattered to [B,H,S,HD]
//         buffers (matrix 0 = Q, scaled 0.125*log2e).
// MODE 1: Wo (grid 384), fp32 out row-major.
// ---------------------------------------------------------------------------
struct BiasArgs { const float* bias[5]; };

template <int MODE>
__global__ __launch_bounds__(256) void gemm_bf16(
    const u16* __restrict__ A, const u16* __restrict__ WT, BiasArgs ba,
    u16* __restrict__ outb, float* __restrict__ outf) {
  __shared__ __align__(16) u16 As[128 * 64];
  __shared__ __align__(16) u16 Bs[128 * 64];
  const int tid = threadIdx.x;
  const int w = tid >> 6, l = tid & 63;
  const int lq = l & 15, g = l >> 4;

  // bijective XCD swizzle (nwg % 8 == 0 in both modes)
  const int NB = (MODE == 0) ? 30 : 6;
  const int nwg = NB * 64;
  const int cpx = nwg >> 3;
  const int id = (int)blockIdx.x;
  const int swz = (id & 7) * cpx + (id >> 3);
  const int bn = swz % NB, bm = swz / NB;

  const int m0 = bm * 128;
  const int wsel = (MODE == 0) ? (bn / 6) : 0;
  const int n0 = (MODE == 0) ? ((bn % 6) * 128) : (bn * 128);
  const int nw0 = bn * 128;
  const float* __restrict__ bias = ba.bias[wsel];
  const int wm = w >> 1, wn = w & 1;

  f32x4 acc[4][4];
#pragma unroll
  for (int i = 0; i < 4; i++)
#pragma unroll
    for (int j = 0; j < 4; j++) acc[i][j] = (f32x4){0.f, 0.f, 0.f, 0.f};

  for (int k0 = 0; k0 < 768; k0 += 64) {
    __syncthreads();
    // stage As/Bs: 16 gload_lds each; LDS linear, global source
    // inverse-swizzled: LDS slot sl holds global slot sl^(row&7).
#pragma unroll
    for (int j = 0; j < 4; j++) {
      const int ci = (j * 4 + w) * 64 + l;
      const int row = ci >> 3, sl = ci & 7;
      const int src = sl ^ (row & 7);
      load_lds16(A + (size_t)(m0 + row) * 768 + k0 + src * 8,
                 (char*)As + (j * 4 + w) * 1024);
    }
#pragma unroll
    for (int j = 0; j < 4; j++) {
      const int ci = (j * 4 + w) * 64 + l;
      const int row = ci >> 3, sl = ci & 7;
      const int src = sl ^ (row & 7);
      load_lds16(WT + (size_t)(nw0 + row) * 768 + k0 + src * 8,
                 (char*)Bs + (j * 4 + w) * 1024);
    }
    asm volatile("s_waitcnt vmcnt(0)" ::: "memory");
    __syncthreads();
#pragma unroll
    for (int s = 0; s < 2; s++) {
      s16x8 af[4], bf[4];
#pragma unroll
      for (int mi = 0; mi < 4; mi++) {
        const int r = wm * 64 + mi * 16 + lq;
        af[mi] = *(const s16x8*)(As + r * 64 + (((s * 4 + g) ^ (r & 7)) * 8));
      }
#pragma unroll
      for (int nj = 0; nj < 4; nj++) {
        const int r = wn * 64 + nj * 16 + lq;
        bf[nj] = *(const s16x8*)(Bs + r * 64 + (((s * 4 + g) ^ (r & 7)) * 8));
      }
#pragma unroll
      for (int mi = 0; mi < 4; mi++)
#pragma unroll
        for (int nj = 0; nj < 4; nj++)
          acc[mi][nj] = __builtin_amdgcn_mfma_f32_16x16x32_bf16(
              af[mi], bf[nj], acc[mi][nj], 0, 0, 0);
    }
  }

  const int rbase = g * 4;
  const int cl = lq;
  if (MODE == 0) {
    const float scale = (wsel == 0) ? QSCALE : 1.0f;
    u16* outw = outb + (size_t)wsel * ((size_t)BB * HH * SS * HDD);
#pragma unroll
    for (int nj = 0; nj < 4; nj++) {
      const int c = n0 + wn * 64 + nj * 16 + cl;
      const float bv = bias[c];
      const int h = c >> 6, hd = c & 63;
#pragma unroll
      for (int mi = 0; mi < 4; mi++) {
#pragma unroll
        for (int r = 0; r < 4; r++) {
          const int m = m0 + wm * 64 + mi * 16 + rbase + r;
          const int b = m >> 12, s = m & 4095;
          outw[((size_t)(b * HH + h) * SS + s) * HDD + hd] =
              f2b((acc[mi][nj][r] + bv) * scale);
        }
      }
    }
  } else {
#pragma unroll
    for (int nj = 0; nj < 4; nj++) {
      const int c = n0 + wn * 64 + nj * 16 + cl;
      const float bv = bias[c];
#pragma unroll
      for (int mi = 0; mi < 4; mi++) {
#pragma unroll
        for (int r = 0; r < 4; r++) {
          const int m = m0 + wm * 64 + mi * 16 + rbase + r;
          outf[(size_t)m * 768 + c] = acc[mi][nj][r] + bv;
        }
      }
    }
  }
}

// ---------------------------------------------------------------------------
// qg projection: QG[bh][qi][d] = (hs[b,qi,:] @ Wqg + bqg)[h*64+d] * QSCALE
// for qi<8; rows 8..15 zeroed. bf16 out. Grid = 24 (bh).
// ---------------------------------------------------------------------------
__global__ __launch_bounds__(256) void qg_proj(
    const float* __restrict__ hs, const float* __restrict__ Wqg,
    const float* __restrict__ bqg, u16* __restrict__ QG) {
  __shared__ float hsL[8][768];
  const int bh = blockIdx.x;
  const int b = bh / HH, h = bh % HH;
  const int t = threadIdx.x;
#pragma unroll
  for (int i = 0; i < 6; i++) {
    int idx = t + i * 256;  // 1536 float4 = 8 rows x 192
    int row = idx / 192, c4 = idx % 192;
    *(float4*)&hsL[row][c4 * 4] =
        *(const float4*)(hs + ((size_t)b * SS + row) * DD + c4 * 4);
  }
  __syncthreads();
#pragma unroll
  for (int rep = 0; rep < 2; rep++) {
    int qi = rep * 4 + (t >> 6);
    int d = t & 63, n = h * 64 + d;
    float acc = bqg[n];
    for (int k = 0; k < DD; k++)
      acc = fmaf(hsL[qi][k], Wqg[(size_t)k * DD + n], acc);
    QG[((size_t)bh * 16 + qi) * 64 + d] = f2b(acc * QSCALE);
  }
#pragma unroll
  for (int i = 0; i < 2; i++) {
    int idx = t + i * 256;
    int row = 8 + (idx >> 6), d = idx & 63;
    QG[((size_t)bh * 16 + row) * 64 + d] = 0;
  }
}

// ---------------------------------------------------------------------------
// MFMA attention. GLOBAL=0: banded sliding-window + global-key mini-tile,
// one WG = 64 queries of one (b,h); 10 key tiles of 64; writes normalized
// bf16 ATT [B,S,D]. GLOBAL=1: global tokens (16 padded queries) vs 512-key
// split; per-wave tiles; writes fp32 partials (num, den).
// ---------------------------------------------------------------------------
template <int GLOBAL>
__global__ __launch_bounds__(256) void attn_mfma(
    const u16* __restrict__ Q, const u16* __restrict__ K,
    const u16* __restrict__ V, const int* __restrict__ amask,
    u16* __restrict__ ATT, float* __restrict__ Pnum,
    float* __restrict__ Pden) {
  extern __shared__ __align__(16) char smem[];
  const int tid = threadIdx.x;
  const int w = tid >> 6, lane = tid & 63;
  const int lq = lane & 15, g = lane >> 4;
  const int h = blockIdx.y, b = blockIdx.z;
  const int bh = b * HH + h;
  const size_t bhs = (size_t)bh * SS;
  const int q0 = GLOBAL ? 0 : (int)blockIdx.x * 64;
  const int split = GLOBAL ? (int)blockIdx.x : 0;

  char* Kl;
  char* VT;
  if constexpr (GLOBAL) {
    Kl = smem + w * 16384;
    VT = Kl + 8192;
  } else {
    Kl = smem;
    VT = smem + 8192;
  }

  s16x8 qf[2];
  {
    const u16* qp = GLOBAL ? (Q + ((size_t)bh * 16 + lq) * 64)
                           : (Q + (bhs + q0 + w * 16 + lq) * 64);
    qf[0] = *(const s16x8*)(qp + g * 8);
    qf[1] = *(const s16x8*)(qp + 32 + g * 8);
  }

  f32x4 oacc[4];
#pragma unroll
  for (int i = 0; i < 4; i++) oacc[i] = (f32x4){0.f, 0.f, 0.f, 0.f};
  float denom = 0.f;

  const int NT = GLOBAL ? 2 : 10;
  for (int kt = 0; kt < NT; kt++) {
    int j0, klimit;
    bool bandfree;
    if constexpr (GLOBAL) {
      j0 = split * 512 + (w * 2 + kt) * 64;
      bandfree = true;
      klimit = 64;
    } else {
      if (kt < 9) { j0 = q0 - 256 + kt * 64; bandfree = false; klimit = 64; }
      else        { j0 = 0;                  bandfree = true;  klimit = 8; }
    }

    int jm = j0 + lane;
    int mv = ((unsigned)jm < (unsigned)SS) ? amask[b * SS + jm] : -1;
    bool okk = (mv >= 0) && (lane < klimit);
    unsigned long long vm = __ballot(okk);

    // ---- staging ----
    if constexpr (GLOBAL) {
      asm volatile("s_waitcnt lgkmcnt(0)" ::: "memory");
      const u16* Ks = K + bhs * 64 + (size_t)j0 * 64;
#pragma unroll
      for (int i = 0; i < 8; i++) {
        int ci = i * 64 + lane;
        int row = ci >> 3, cc = ci & 7, cs = cc ^ (row & 7);
        load_lds16(Ks + row * 64 + cs * 8, Kl + i * 1024);
      }
      const u16* Vs = V + bhs * 64 + (size_t)j0 * 64;
#pragma unroll
      for (int p = 0; p < 8; p++) {
        u16x8 vv = *(const u16x8*)(Vs + (size_t)lane * 64 + p * 8);
#pragma unroll
        for (int e = 0; e < 8; e++)
          *(u16*)(VT + (p * 8 + e) * 128 + ((lane * 2) ^ (e << 4))) = vv[e];
      }
      asm volatile("s_waitcnt vmcnt(0) lgkmcnt(0)" ::: "memory");
    } else {
      __syncthreads();
      if (j0 >= 0 && j0 + 64 <= SS) {
        const u16* Ks = K + bhs * 64 + (size_t)j0 * 64;
#pragma unroll
        for (int i = 0; i < 2; i++) {
          int ci = (i * 4 + w) * 64 + lane;
          int row = ci >> 3, cc = ci & 7, cs = cc ^ (row & 7);
          load_lds16(Ks + row * 64 + cs * 8, Kl + (i * 4 + w) * 1024);
        }
      } else {
#pragma unroll
        for (int i = 0; i < 2; i++) {
          int ci = (i * 4 + w) * 64 + lane;
          int row = ci >> 3, cc = ci & 7, cs = cc ^ (row & 7);
          int jj = j0 + row;
          u16x8 val;
#pragma unroll
          for (int e = 0; e < 8; e++) val[e] = 0;
          if ((unsigned)jj < (unsigned)SS)
            val = *(const u16x8*)(K + (bhs + jj) * 64 + cs * 8);
          *(u16x8*)(Kl + ci * 16) = val;
        }
      }
#pragma unroll
      for (int p = 0; p < 2; p++) {
        int d0 = p * 32 + w * 8;
        int jj = j0 + lane;
        u16x8 vv;
#pragma unroll
        for (int e = 0; e < 8; e++) vv[e] = 0;
        if ((unsigned)jj < (unsigned)SS)
          vv = *(const u16x8*)(V + (bhs + jj) * 64 + d0);
#pragma unroll
        for (int e = 0; e < 8; e++)
          *(u16*)(VT + (d0 + e) * 128 + ((lane * 2) ^ (e << 4))) = vv[e];
      }
      asm volatile("s_waitcnt vmcnt(0)" ::: "memory");
      __syncthreads();
    }

    // ---- QK^T ----
    f32x4 sc[4];
#pragma unroll
    for (int i = 0; i < 4; i++) sc[i] = (f32x4){0.f, 0.f, 0.f, 0.f};
#pragma unroll
    for (int s = 0; s < 2; s++) {
#pragma unroll
      for (int ks = 0; ks < 4; ks++) {
        s16x8 kf = *(const s16x8*)(Kl + (ks * 16 + lq) * 128 +
                                   (((s * 4 + g) ^ (lq & 7)) << 4));
        sc[ks] = __builtin_amdgcn_mfma_f32_16x16x32_bf16(kf, qf[s], sc[ks],
                                                          0, 0, 0);
      }
    }

    // ---- mask + exp2 -> P ----
    {
      const unsigned mlo = (unsigned)vm, mhi = (unsigned)(vm >> 32);
      const int q_abs = q0 + w * 16 + lq;
      bool allin = bandfree;
      if constexpr (!GLOBAL) {
        const int qw = q0 + w * 16;
        allin = bandfree || (j0 >= qw - 241 && j0 <= qw + 193);
      }
      const bool fast = (vm == ~0ull) && allin;
      const int ddq = j0 + g * 4 - q_abs;
      const int gsh = g * 4;
      if (fast) {
#pragma unroll
        for (int ks = 0; ks < 4; ks++)
#pragma unroll
          for (int r = 0; r < 4; r++) {
            float p = fexp2(sc[ks][r]);
            sc[ks][r] = p;
            denom += p;
          }
      } else {
#pragma unroll
        for (int ks = 0; ks < 4; ks++)
#pragma unroll
          for (int r = 0; r < 4; r++) {
            float e = fexp2(sc[ks][r]);
            unsigned bit =
                ((ks < 2 ? mlo : mhi) >> (gsh + ((ks & 1) * 16 + r))) & 1u;
            bool ok = bit && (allin ||
                              (unsigned)(ddq + ks * 16 + r + 256) <= 512u);
            float p = ok ? e : 0.f;
            sc[ks][r] = p;
            denom += p;
          }
      }
    }

    // ---- P^T fragments + PV ----
#pragma unroll
    for (int s = 0; s < 2; s++) {
      const int srcA = lq + ((g & 1) << 5);
      const bool hiSel = g >= 2;
      float L[4], H[4];
#pragma unroll
      for (int r = 0; r < 4; r++) {
        float a0 = __shfl(sc[2 * s][r], srcA);
        float a1 = __shfl(sc[2 * s + 1][r], srcA);
        L[r] = hiSel ? a1 : a0;
        float b0 = __shfl(sc[2 * s][r], srcA + 16);
        float b1 = __shfl(sc[2 * s + 1][r], srcA + 16);
        H[r] = hiSel ? b1 : b0;
      }
      union { unsigned u[4]; s16x8 v; } pf;
      pf.u[0] = pk_bf16(L[0], L[1]);
      pf.u[1] = pk_bf16(L[2], L[3]);
      pf.u[2] = pk_bf16(H[0], H[1]);
      pf.u[3] = pk_bf16(H[2], H[3]);
#pragma unroll
      for (int dblk = 0; dblk < 4; dblk++) {
        s16x8 vf = *(const s16x8*)(VT + (dblk * 16 + lq) * 128 +
                                   (((s * 4 + g) ^ (lq & 7)) << 4));
        oacc[dblk] = __builtin_amdgcn_mfma_f32_16x16x32_bf16(vf, pf.v,
                                                              oacc[dblk],
                                                              0, 0, 0);
      }
    }
  }

  // ---- epilogue ----
  denom += __shfl_xor(denom, 16);
  denom += __shfl_xor(denom, 32);
  if constexpr (!GLOBAL) {
    const int q_abs = q0 + w * 16 + lq;
    const float rowscale = (amask[b * SS + q_abs] >= 0) ? (1.f / denom) : 0.f;
    u16* orow = ATT + ((size_t)b * SS + q_abs) * DD + h * 64;
#pragma unroll
    for (int dblk = 0; dblk < 4; dblk++) {
      u16x4 o;
#pragma unroll
      for (int r = 0; r < 4; r++) o[r] = f2b(oacc[dblk][r] * rowscale);
      *(u16x4*)(orow + dblk * 16 + g * 4) = o;
    }
  } else {
    const int pidx = split * 4 + w;
    float* np = Pnum + ((size_t)bh * 32 + pidx) * 1024;
#pragma unroll
    for (int dblk = 0; dblk < 4; dblk++)
#pragma unroll
      for (int r = 0; r < 4; r++)
        np[(dblk * 16 + g * 4 + r) * 16 + lq] = oacc[dblk][r];
    Pden[((size_t)bh * 32 + pidx) * 16 + lq] = denom;
  }
}

// ---------------------------------------------------------------------------
// Merge global-token partials and overwrite ATT rows < G.
// ---------------------------------------------------------------------------
__global__ __launch_bounds__(512) void gmerge(const float* __restrict__ Pnum,
                                              const float* __restrict__ Pden,
                                              u16* __restrict__ ATT) {
  const int bh = blockIdx.x;
  const int b = bh / HH, h = bh % HH;
  const int t = threadIdx.x;
  const int q = t >> 6, d = t & 63;
  float num = 0.f, den = 0.f;
#pragma unroll 4
  for (int p = 0; p < 32; p++) {
    num += Pnum[((size_t)bh * 32 + p) * 1024 + d * 16 + q];
    den += Pden[((size_t)bh * 32 + p) * 16 + q];
  }
  ATT[((size_t)b * SS + q) * DD + h * 64 + d] = f2b(num / den);
}

// ---------------------------------------------------------------------------
extern "C" void kernel_launch(void* const* d_in, const int* in_sizes, int n_in,
                              void* d_out, int out_size, void* d_ws,
                              size_t ws_size, hipStream_t stream) {
  const float* hs = (const float*)d_in[0];
  const int* amask = (const int*)d_in[1];
  const float* Wq = (const float*)d_in[2];
  const float* bq = (const float*)d_in[3];
  const float* Wk = (const float*)d_in[4];
  const float* bk = (const float*)d_in[5];
  const float* Wv = (const float*)d_in[6];
  const float* bv = (const float*)d_in[7];
  const float* Wqg = (const float*)d_in[8];
  const float* bqg = (const float*)d_in[9];
  const float* Wkg = (const float*)d_in[10];
  const float* bkg = (const float*)d_in[11];
  const float* Wvg = (const float*)d_in[12];
  const float* bvg = (const float*)d_in[13];
  const float* Wo = (const float*)d_in[14];
  const float* bo = (const float*)d_in[15];
  float* out = (float*)d_out;

  char* ws = (char*)d_ws;
  const size_t QSZB = (size_t)BB * HH * SS * HDD * 2;  // 12582912 B
  u16* Qb = (u16*)(ws + 0);
  u16* Kb = (u16*)(ws + QSZB);
  u16* Vb = (u16*)(ws + 2 * QSZB);
  u16* KGb = (u16*)(ws + 3 * QSZB);
  u16* VGb = (u16*)(ws + 4 * QSZB);
  u16* Ab = (u16*)(ws + 5 * QSZB);
  u16* WTb = (u16*)(ws + 6 * QSZB);                     // 7077888 B
  u16* ATTb = (u16*)(ws + 6 * QSZB + 7077888);          // QSZB
  u16* QGb = (u16*)(ws + 7 * QSZB + 7077888);           // 49152 B
  float* Pnum = (float*)(ws + 7 * QSZB + 7077888 + 49152);   // 3145728 B
  float* Pden = (float*)(ws + 7 * QSZB + 7077888 + 49152 + 3145728);  // 49152

  // 1) convert hs -> bf16 A
  hipLaunchKernelGGL(cvt_f32_bf16, dim3(3072), dim3(256), 0, stream, hs, Ab,
                     (int)((size_t)BB * SS * DD / 8));

  // 2) transpose+convert 6 weight matrices -> WT[mat][n][k] bf16
  WtArgs wa;
  wa.W[0] = Wq; wa.W[1] = Wk; wa.W[2] = Wv;
  wa.W[3] = Wkg; wa.W[4] = Wvg; wa.W[5] = Wo;
  hipLaunchKernelGGL(transpose_wt, dim3(12, 12, 6), dim3(256), 0, stream, wa,
                     WTb);

  // 3) fused projections (bf16 MFMA): Q,K,V,KG,VG  (Q scaled 0.125*log2e)
  BiasArgs b0;
  b0.bias[0] = bq; b0.bias[1] = bk; b0.bias[2] = bv;
  b0.bias[3] = bkg; b0.bias[4] = bvg;
  hipLaunchKernelGGL((gemm_bf16<0>), dim3(1920), dim3(256), 0, stream, Ab,
                     WTb, b0, Qb, (float*)nullptr);

  // 4) qg projection -> QGb
  hipLaunchKernelGGL(qg_proj, dim3(24), dim3(256), 0, stream, hs, Wqg, bqg,
                     QGb);

  // 5) global-token attention partials (reads KGb/VGb/QGb)
  hipLaunchKernelGGL((attn_mfma<1>), dim3(8, HH, BB), dim3(256), 65536,
                     stream, QGb, KGb, VGb, amask, (u16*)nullptr, Pnum, Pden);

  // 6) banded attention -> ATT (bf16)
  hipLaunchKernelGGL((attn_mfma<0>), dim3(64, HH, BB), dim3(256), 16384,
                     stream, Qb, Kb, Vb, amask, ATTb, (float*)nullptr,
                     (float*)nullptr);

  // 7) merge global-token rows into ATT
  hipLaunchKernelGGL(gmerge, dim3(24), dim3(512), 0, stream, Pnum, Pden, ATTb);

  // 8) output projection (bf16 MFMA, fp32 out)
  BiasArgs b1;
  for (int i = 0; i < 5; i++) b1.bias[i] = bo;
  hipLaunchKernelGGL((gemm_bf16<1>), dim3(384), dim3(256), 0, stream, ATTb,
                     WTb + (size_t)5 * 768 * 768, b1, (u16*)nullptr, out);
}